// Round 5
// baseline (260.033 us; speedup 1.0000x reference)
//
#include <hip/hip_runtime.h>
#include <hip/hip_bf16.h>

typedef __attribute__((ext_vector_type(8))) short short8;
typedef __attribute__((ext_vector_type(4))) float floatx4;
typedef __attribute__((ext_vector_type(4))) int intx4;
typedef __attribute__((ext_vector_type(2))) int intx2;

#define D_MODEL 1024
#define SEQ     2048
#define NB      2
#define NH      16
#define HD      64
#define MROWS   4096   // NB*SEQ
#define CZ      (0.125f * 1.44269504f)   // 1/sqrt(64) * log2(e)

__device__ __forceinline__ floatx4 mfma_bf16(short8 a, short8 b, floatx4 c) {
  return __builtin_amdgcn_mfma_f32_16x16x32_bf16(a, b, c, 0, 0, 0);
}

// async global -> LDS, 16 B per lane. LDS dest = wave-uniform base + lane*16.
__device__ __forceinline__ void dma16(const __hip_bfloat16* g, __hip_bfloat16* l) {
  __builtin_amdgcn_global_load_lds(
      (const __attribute__((address_space(1))) void*)g,
      (__attribute__((address_space(3))) void*)l, 16, 0, 0);
}
#define WAIT_VM(n)  __asm__ __volatile__("s_waitcnt vmcnt(" #n ")" ::: "memory")
#define BARRIER()   __asm__ __volatile__("s_barrier" ::: "memory")
#define WAIT_LGKM() __asm__ __volatile__("s_waitcnt lgkmcnt(0)" ::: "memory")

// round-half-up bf16 pair pack (used by GEMM epilogues)
__device__ __forceinline__ int pack2bf(float a, float b) {
  unsigned ua = __builtin_bit_cast(unsigned, a) + 0x8000u;
  unsigned ub = __builtin_bit_cast(unsigned, b) + 0x8000u;
  return (int)__builtin_amdgcn_perm(ub, ua, 0x07060302u);
}

// single-instruction bf16 pair pack (RNE): dst.lo = bf16(a), dst.hi = bf16(b)
__device__ __forceinline__ int cvtpk(float a, float b) {
  int r;
  __asm__("v_cvt_pk_bf16_f32 %0, %1, %2" : "=v"(r) : "v"(a), "v"(b));
  return r;
}

// ---------------- prep: W transpose (z<4) + x fp32->bf16 (z==4) ----------------
__global__ void prep_kernel(const float* __restrict__ x, __hip_bfloat16* __restrict__ xb,
                            const float* __restrict__ W0, const float* __restrict__ W1,
                            const float* __restrict__ W2, const float* __restrict__ W3,
                            __hip_bfloat16* __restrict__ T0, __hip_bfloat16* __restrict__ T1,
                            __hip_bfloat16* __restrict__ T2, __hip_bfloat16* __restrict__ T3) {
  const int z = blockIdx.z;
  if (z == 4) {
    const int tid = threadIdx.y * 32 + threadIdx.x;
    const int base = ((blockIdx.y * 32 + blockIdx.x) * 256 + tid) * 16;
#pragma unroll
    for (int c = 0; c < 4; c++) {
      float4 v = *(const float4*)(x + base + c * 4);
      __hip_bfloat16 tmp[4];
      tmp[0] = __float2bfloat16(v.x);
      tmp[1] = __float2bfloat16(v.y);
      tmp[2] = __float2bfloat16(v.z);
      tmp[3] = __float2bfloat16(v.w);
      *(ushort4*)(xb + base + c * 4) = *(ushort4*)tmp;
    }
    return;
  }
  const float* W = (z == 0) ? W0 : (z == 1) ? W1 : (z == 2) ? W2 : W3;
  __hip_bfloat16* Wt = (z == 0) ? T0 : (z == 1) ? T1 : (z == 2) ? T2 : T3;
  __shared__ float tile[32][33];
  int k0 = blockIdx.x * 32, n0 = blockIdx.y * 32;
  int tx = threadIdx.x, ty = threadIdx.y;  // block (32,8)
#pragma unroll
  for (int i = 0; i < 4; i++)
    tile[ty + 8 * i][tx] = W[(size_t)(k0 + ty + 8 * i) * D_MODEL + n0 + tx];
  __syncthreads();
#pragma unroll
  for (int i = 0; i < 4; i++)
    Wt[(size_t)(n0 + ty + 8 * i) * D_MODEL + k0 + tx] = __float2bfloat16(tile[tx][ty + 8 * i]);
}

// ---------------- GEMM: Y = (X @ W + b) * scale ----------------
// Triple-buffered LDS staging with depth-2 prefetch + counted vmcnt + granule
// XOR-swizzle (phys_granule = logical ^ ((row>>1)&3)): linear LDS dest,
// inverse-swizzled GLOBAL source, swizzled read column.
// MODE 0: MT=128; grid (8 n, 3 z, 32 m). z=0 -> Q bf16 [bh][s][d] * CZ;
//         z=1 -> K bf16 [bh][s][d]; z=2 -> V^T bf16 [bh][d][s].
// MODE 1: MT=64; grid (8 n, 1, 64 m). fp32 row-major out.
template <int MODE>
__global__ __launch_bounds__(256) void gemm_kernel(
    const __hip_bfloat16* __restrict__ X,
    const __hip_bfloat16* __restrict__ Wt0, const __hip_bfloat16* __restrict__ Wt1,
    const __hip_bfloat16* __restrict__ Wt2,
    const float* __restrict__ b0, const float* __restrict__ b1, const float* __restrict__ b2,
    void* __restrict__ out0, void* __restrict__ out1, void* __restrict__ out2) {
  constexpr int MT = (MODE == 0) ? 128 : 64;
  constexpr int I = MT / 32;
  constexpr int NKT = D_MODEL / 32;
  constexpr int STAGE_BYTES = 3 * (MT * 32 + 128 * 32) * 2;
  constexpr int EPI_BYTES = 64 * 132 * 4;
  constexpr int SMEM_BYTES = (STAGE_BYTES > EPI_BYTES) ? STAGE_BYTES : EPI_BYTES;

  const int z = blockIdx.y;
  const __hip_bfloat16* Wt = (z == 0) ? Wt0 : (z == 1) ? Wt1 : Wt2;
  const float* bias = (z == 0) ? b0 : (z == 1) ? b1 : b2;
  void* outp = (z == 0) ? out0 : (z == 1) ? out1 : out2;
  const float scale = (MODE == 0 && z == 0) ? CZ : 1.f;

  __shared__ __attribute__((aligned(16))) char smem[SMEM_BYTES];
  __hip_bfloat16* As = (__hip_bfloat16*)smem;                       // 3 bufs of MT*32
  __hip_bfloat16* Bs = (__hip_bfloat16*)smem + 3 * MT * 32;         // 3 bufs of 128*32
  float* Es = (float*)smem;                                         // epilogue scratch

  const int n0 = blockIdx.x * 128;
  const int m0 = blockIdx.z * MT;
  const int t = threadIdx.x;
  const int lane = t & 63, w = t >> 6;
  const int wm = (w >> 1) * (MT / 2), wn = (w & 1) * 64;
  const int lr = lane & 15;
  const int lq = lane >> 4;

  const __hip_bfloat16* Xp = X + (size_t)m0 * D_MODEL;
  const __hip_bfloat16* Wp = Wt + (size_t)n0 * D_MODEL;

  const int lrow = lane >> 2;
  // inverse-swizzled source granule: LDS slot (lane&3) of row lrow receives
  // logical granule (lane&3) ^ ((lrow>>1)&3)
  const int skg = (((lane & 3) ^ ((lane >> 3) & 3)) << 3);
  const int srowA = ((MT == 128) ? (w << 5) : (w << 4)) + lrow;
  const int sbA0 = (((MT == 128) ? (w << 5) : (w << 4)) << 5);
  const int sbA1 = sbA0 + (16 << 5);
  const int srowB = (w << 5) + lrow;
  const int sbB0 = ((w << 5) << 5);
  const int sbB1 = sbB0 + (16 << 5);

#define STAGE_G(kt_, buf_)                                                              \
  {                                                                                     \
    const int kn_ = (kt_) * 32;                                                         \
    __hip_bfloat16* A_ = As + (buf_) * (MT * 32);                                       \
    __hip_bfloat16* B_ = Bs + (buf_) * (128 * 32);                                      \
    dma16(Xp + (size_t)srowA * D_MODEL + kn_ + skg, A_ + sbA0);                         \
    if (MT == 128) dma16(Xp + (size_t)(srowA + 16) * D_MODEL + kn_ + skg, A_ + sbA1);   \
    dma16(Wp + (size_t)srowB * D_MODEL + kn_ + skg, B_ + sbB0);                         \
    dma16(Wp + (size_t)(srowB + 16) * D_MODEL + kn_ + skg, B_ + sbB1);                  \
  }

  floatx4 acc[I][4];
#pragma unroll
  for (int i = 0; i < I; i++)
#pragma unroll
    for (int j = 0; j < 4; j++) acc[i][j] = (floatx4){0.f, 0.f, 0.f, 0.f};

  STAGE_G(0, 0);
  STAGE_G(1, 1);

  // swizzled read column (logical granule lq of row ...+lr lives at slot lq^((lr>>1)&3))
  const int rcol = ((lq ^ ((lr >> 1) & 3)) << 3);

  int cb = 0;
  for (int kt = 0; kt < NKT; kt++) {
    if (kt < NKT - 1) {
      if constexpr (MODE == 0) WAIT_VM(4);
      else                     WAIT_VM(3);
    } else {
      WAIT_VM(0);
    }
    BARRIER();
    if (kt + 2 < NKT) {
      const int nb = (cb == 0) ? 2 : cb - 1;
      STAGE_G(kt + 2, nb);
    }
    const __hip_bfloat16* Ac = As + cb * (MT * 32);
    const __hip_bfloat16* Bc = Bs + cb * (128 * 32);
    short8 af[I], bfr[4];
#pragma unroll
    for (int i = 0; i < I; i++) af[i] = *(const short8*)&Ac[(wm + i * 16 + lr) * 32 + rcol];
#pragma unroll
    for (int j = 0; j < 4; j++) bfr[j] = *(const short8*)&Bc[(wn + j * 16 + lr) * 32 + rcol];
#pragma unroll
    for (int i = 0; i < I; i++)
#pragma unroll
      for (int j = 0; j < 4; j++) acc[i][j] = mfma_bf16(af[i], bfr[j], acc[i][j]);
    cb = (cb == 2) ? 0 : cb + 1;
  }
#undef STAGE_G

  // ---- epilogue via LDS round-trip (staging buffers are free now) ----
  float bvj[4];
#pragma unroll
  for (int j = 0; j < 4; j++) bvj[j] = bias[n0 + wn + j * 16 + lr];

  if constexpr (MODE == 1) {
    // fp32 row-major out. Scratch [64 m][132].
    BARRIER();
#pragma unroll
    for (int i = 0; i < I; i++) {
      const int rowb = wm + i * 16 + lq * 4;
#pragma unroll
      for (int j = 0; j < 4; j++)
#pragma unroll
        for (int r = 0; r < 4; r++)
          Es[(rowb + r) * 132 + wn + j * 16 + lr] = acc[i][j][r] + bvj[j];
    }
    WAIT_LGKM();
    BARRIER();
    const int L = t >> 2, nseg = (t & 3) * 32;
    float* op = (float*)outp + (size_t)(m0 + L) * D_MODEL + n0 + nseg;
    const float* src = &Es[L * 132 + nseg];
#pragma unroll
    for (int k = 0; k < 8; k++) *(float4*)(op + 4 * k) = *(const float4*)(src + 4 * k);
  } else if (z != 2) {
    // Q/K bf16 [bh][s][d]. Two chunks of i in {2c, 2c+1}; scratch [64 m][132].
    for (int c = 0; c < 2; c++) {
      BARRIER();
#pragma unroll
      for (int i2 = 0; i2 < 2; i2++) {
        const int i = 2 * c + i2;
        const int rowb = (w >> 1) * 32 + i2 * 16 + lq * 4;
#pragma unroll
        for (int j = 0; j < 4; j++)
#pragma unroll
          for (int r = 0; r < 4; r++)
            Es[(rowb + r) * 132 + wn + j * 16 + lr] = (acc[i][j][r] + bvj[j]) * scale;
      }
      WAIT_LGKM();
      BARRIER();
      const int L = t >> 2, nseg = (t & 3) * 32;
      const int m = m0 + ((L >> 5) << 6) + (c << 5) + (L & 31);
      const int bb = m >> 11, s = m & 2047;
      const int nn = n0 + nseg;
      __hip_bfloat16* op = (__hip_bfloat16*)outp +
          (((size_t)(bb * NH + (nn >> 6)) * SEQ + s) * HD + (nn & 63));
      const float* src = &Es[L * 132 + nseg];
#pragma unroll
      for (int k = 0; k < 4; k++) {
        intx4 pk;
        pk[0] = pack2bf(src[8 * k + 0], src[8 * k + 1]);
        pk[1] = pack2bf(src[8 * k + 2], src[8 * k + 3]);
        pk[2] = pack2bf(src[8 * k + 4], src[8 * k + 5]);
        pk[3] = pack2bf(src[8 * k + 6], src[8 * k + 7]);
        *(intx4*)(op + 8 * k) = pk;
      }
    }
  } else {
    // V^T bf16 [bh][d][s]. Two chunks of j in {2c, 2c+1}; scratch [64 n][132 m].
    for (int c = 0; c < 2; c++) {
      BARRIER();
#pragma unroll
      for (int j2 = 0; j2 < 2; j2++) {
        const int j = 2 * c + j2;
        const int nl = ((w & 1) << 5) + (j2 << 4) + lr;
#pragma unroll
        for (int i = 0; i < I; i++) {
          const int moff = (w >> 1) * 64 + i * 16 + lq * 4;
          floatx4 v = acc[i][j];
          v[0] += bvj[j]; v[1] += bvj[j]; v[2] += bvj[j]; v[3] += bvj[j];
          *(floatx4*)&Es[nl * 132 + moff] = v;
        }
      }
      WAIT_LGKM();
      BARRIER();
      const int nl = t >> 2, mseg = (t & 3) * 32;
      const int n = n0 + ((nl >> 5) << 6) + (c << 5) + (nl & 31);
      const int s0 = m0 & 2047, bb = m0 >> 11;
      __hip_bfloat16* op = (__hip_bfloat16*)outp +
          (((size_t)(bb * NH + (n >> 6)) * HD + (n & 63)) * SEQ + s0 + mseg);
      const float* src = &Es[nl * 132 + mseg];
#pragma unroll
      for (int k = 0; k < 4; k++) {
        intx4 pk;
        pk[0] = pack2bf(src[8 * k + 0], src[8 * k + 1]);
        pk[1] = pack2bf(src[8 * k + 2], src[8 * k + 3]);
        pk[2] = pack2bf(src[8 * k + 4], src[8 * k + 5]);
        pk[3] = pack2bf(src[8 * k + 6], src[8 * k + 7]);
        *(intx4*)(op + 8 * k) = pk;
      }
    }
  }
}

// ---------------- flash attention, causal, no-max softmax, NO-STAGING ----------------
// Grid (32 bh, 32 qt), qt = 31-blockIdx.y. QBLK=64: wr = w&1 (32-q half),
// wb = w>>1 (interleaved 16-key groups of a 64-key tile).
// K/V are read DIRECTLY from global each tile -- no LDS staging, no main-loop
// barriers/vmcnt at all. Rationale: per-bh K/V = 512 KB and blockIdx%8 == bh%8
// pins each bh to one XCD, so all K/V reads are ~L2-local; waves run as fully
// independent streaming MFMA chains and TLP (16 waves/CU) hides latency.
// The kappa-permuted zero-shuffle PV needs no swizzle when reading from global:
//   kf[ks][nt] = K[(kt*64 + nt*32 + wb*16 + lr)*64 + ks*32 + lq*8]  (16 B/lane)
//   vfr[dt]    = V^T[(dt*16+lr)*SEQ + kt*64 + wb*16 + lq*4 (+32)]   (2x 8 B/lane)
// Row-sums via ones-vector MFMA into lsacc. LDS (32 KB) only for the epilogue
// wb-merge (2 barriers total).
__global__ __launch_bounds__(256, 4) void attn_kernel(
    const __hip_bfloat16* __restrict__ Q, const __hip_bfloat16* __restrict__ Kg,
    const __hip_bfloat16* __restrict__ Vt, __hip_bfloat16* __restrict__ ctx) {
  const int bh = blockIdx.x;
  const int b = bh >> 4, h = bh & 15;
  const int qt = 31 - blockIdx.y;
  const int t = threadIdx.x, lane = t & 63, w = t >> 6;
  const int lr = lane & 15, lq = lane >> 4;
  const int wr = w & 1, wb = w >> 1;

  __shared__ __attribute__((aligned(16))) __hip_bfloat16 Ks[2][64 * 64];   // epilogue scratch
  __shared__ __attribute__((aligned(16))) __hip_bfloat16 VTs[1][64 * 64];  // epilogue scratch

  const __hip_bfloat16* Qb = Q + (size_t)bh * SEQ * HD;
  const __hip_bfloat16* Kb = Kg + (size_t)bh * SEQ * HD;
  const __hip_bfloat16* Vb = Vt + (size_t)bh * HD * SEQ;

  const int qrow0 = qt * 64 + wr * 32;  // this wave's first query row

  // Q fragments
  short8 qf[2][2];  // [rt][ks]
#pragma unroll
  for (int rt = 0; rt < 2; rt++)
#pragma unroll
    for (int ks = 0; ks < 2; ks++)
      qf[rt][ks] = *(const short8*)(Qb + (size_t)(qrow0 + rt * 16 + lr) * HD + ks * 32 + lq * 8);

  const int nkt = qt + 1;

  floatx4 o[2][4];
#pragma unroll
  for (int rt = 0; rt < 2; rt++)
#pragma unroll
    for (int dt = 0; dt < 4; dt++) o[rt][dt] = (floatx4){0.f, 0.f, 0.f, 0.f};
  floatx4 lsacc[2];
  lsacc[0] = (floatx4){0.f, 0.f, 0.f, 0.f};
  lsacc[1] = (floatx4){0.f, 0.f, 0.f, 0.f};

  short8 ones;
#pragma unroll
  for (int j = 0; j < 8; j++) ones[j] = (short)0x3F80;  // bf16 1.0

  // per-wave global read bases (element offsets)
  const __hip_bfloat16* Kfb = Kb + (size_t)((wb << 4) + lr) * HD;         // + kt*64*64 + nt*32*64 + ks*32 + lq*8
  const __hip_bfloat16* Vfb = Vb + (size_t)lr * SEQ + (wb << 4) + (lq << 2);  // + dt*16*SEQ + kt*64 (+32)

  for (int kt = 0; kt < nkt; kt++) {
    const int kw0 = (kt << 6) + (wb << 4);  // wave's first key

    // K frags straight from global (L2-local): row = kt*64 + nt*32 + wb*16 + lr
    short8 kf[2][2];  // [ks][nt]
    const __hip_bfloat16* Kt = Kfb + ((size_t)kt << 12);  // kt*64 rows * 64
#pragma unroll
    for (int nt = 0; nt < 2; nt++) {
      kf[0][nt] = *(const short8*)(Kt + (nt << 11) + (lq << 3));
      kf[1][nt] = *(const short8*)(Kt + (nt << 11) + 32 + (lq << 3));
    }
    // V frags straight from global, kappa-permuted columns: 2x b64 per dt
    short8 vfr[4];
    const __hip_bfloat16* Vtp = Vfb + (kt << 6);
#pragma unroll
    for (int dt = 0; dt < 4; dt++) {
      const __hip_bfloat16* vp = Vtp + (size_t)(dt << 4) * SEQ;
      intx4 vi;
      *(intx2*)&vi = *(const intx2*)vp;
      *(((intx2*)&vi) + 1) = *(const intx2*)(vp + 32);
      vfr[dt] = __builtin_bit_cast(short8, vi);
    }

    // S^T = K Q^T
    floatx4 s[2][2];  // [rt][nt]
#pragma unroll
    for (int rt = 0; rt < 2; rt++)
#pragma unroll
      for (int nt = 0; nt < 2; nt++) s[rt][nt] = (floatx4){0.f, 0.f, 0.f, 0.f};
#pragma unroll
    for (int ks = 0; ks < 2; ks++)
#pragma unroll
      for (int nt = 0; nt < 2; nt++) {
        s[0][nt] = mfma_bf16(kf[ks][nt], qf[0][ks], s[0][nt]);
        s[1][nt] = mfma_bf16(kf[ks][nt], qf[1][ks], s[1][nt]);
      }

    // numerators (mask only near the diagonal) -> bf16 pairs, direct PV B-frag
    const bool need_mask = (kw0 + 47 > qrow0);
    short8 pf[2];
#pragma unroll
    for (int rt = 0; rt < 2; rt++) {
      const int q = qrow0 + rt * 16 + lr;
      intx4 pk;
#pragma unroll
      for (int nt = 0; nt < 2; nt++) {
        const int kbase = (kt << 6) + (nt << 5) + (wb << 4) + (lq << 2);
        float x0 = s[rt][nt][0], x1 = s[rt][nt][1], x2 = s[rt][nt][2], x3 = s[rt][nt][3];
        if (need_mask) {
          x0 = (kbase + 0 <= q) ? x0 : -1e30f;
          x1 = (kbase + 1 <= q) ? x1 : -1e30f;
          x2 = (kbase + 2 <= q) ? x2 : -1e30f;
          x3 = (kbase + 3 <= q) ? x3 : -1e30f;
        }
        const float p0 = __builtin_amdgcn_exp2f(x0);
        const float p1 = __builtin_amdgcn_exp2f(x1);
        const float p2 = __builtin_amdgcn_exp2f(x2);
        const float p3 = __builtin_amdgcn_exp2f(x3);
        pk[2 * nt + 0] = cvtpk(p0, p1);
        pk[2 * nt + 1] = cvtpk(p2, p3);
      }
      pf[rt] = __builtin_bit_cast(short8, pk);
    }

    // row-sums on the MFMA pipe: every output reg = sum_k P^T[k][q]
    lsacc[0] = mfma_bf16(ones, pf[0], lsacc[0]);
    lsacc[1] = mfma_bf16(ones, pf[1], lsacc[1]);

    // O^T += V^T P^T (zero-shuffle, kappa-permuted K-ordering)
#pragma unroll
    for (int dt = 0; dt < 4; dt++) {
      o[0][dt] = mfma_bf16(vfr[dt], pf[0], o[0][dt]);
      o[1][dt] = mfma_bf16(vfr[dt], pf[1], o[1][dt]);
    }
  }

  // ---- epilogue: merge wb partials via LDS ----
  BARRIER();
  if (wb == 1) {
    float* d0 = (float*)&Ks[0][0];   // rt0 partials (8 KB)
    float* d1 = (float*)&Ks[1][0];   // rt1 partials (8 KB)
    float* dl = (float*)&VTs[0][0];  // l partials
    const int base = (wr << 10) + (lane << 4);
#pragma unroll
    for (int dt = 0; dt < 4; dt++) *(floatx4*)&d0[base + (dt << 2)] = o[0][dt];
#pragma unroll
    for (int dt = 0; dt < 4; dt++) *(floatx4*)&d1[base + (dt << 2)] = o[1][dt];
    dl[(wr << 7) + (lane << 1)] = lsacc[0][0];
    dl[(wr << 7) + (lane << 1) + 1] = lsacc[1][0];
    WAIT_LGKM();
  }
  BARRIER();
  if (wb == 0) {
    const float* d0 = (const float*)&Ks[0][0];
    const float* d1 = (const float*)&Ks[1][0];
    const float* dl = (const float*)&VTs[0][0];
    const int base = (wr << 10) + (lane << 4);
#pragma unroll
    for (int dt = 0; dt < 4; dt++) {
      o[0][dt] += *(const floatx4*)&d0[base + (dt << 2)];
      o[1][dt] += *(const floatx4*)&d1[base + (dt << 2)];
    }
    // lsacc already holds the full 32-key wave sum in every reg (ones-MFMA)
    float inv[2];
    inv[0] = 1.f / (lsacc[0][0] + dl[(wr << 7) + (lane << 1)]);
    inv[1] = 1.f / (lsacc[1][0] + dl[(wr << 7) + (lane << 1) + 1]);
#pragma unroll
    for (int rt = 0; rt < 2; rt++) {
      const int row = qrow0 + rt * 16 + lr;
      __hip_bfloat16* cp = ctx + (size_t)b * SEQ * D_MODEL + (size_t)row * D_MODEL + h * HD;
#pragma unroll
      for (int dt = 0; dt < 4; dt++) {
        ushort4 pk;
        __hip_bfloat16* pp = (__hip_bfloat16*)&pk;
#pragma unroll
        for (int r = 0; r < 4; r++) pp[r] = __float2bfloat16(o[rt][dt][r] * inv[rt]);
        *(ushort4*)(cp + (dt << 4) + (lq << 2)) = pk;
      }
    }
  }
}

extern "C" void kernel_launch(void* const* d_in, const int* in_sizes, int n_in,
                              void* d_out, int out_size, void* d_ws, size_t ws_size,
                              hipStream_t stream) {
  const float* x  = (const float*)d_in[0];
  const float* Wq = (const float*)d_in[1];
  const float* bq = (const float*)d_in[2];
  const float* Wk = (const float*)d_in[3];
  const float* bk = (const float*)d_in[4];
  const float* Wv = (const float*)d_in[5];
  const float* bv = (const float*)d_in[6];
  const float* Wo = (const float*)d_in[7];
  const float* bo = (const float*)d_in[8];

  char* ws = (char*)d_ws;
  const size_t MB = 1u << 20;
  __hip_bfloat16* xb  = (__hip_bfloat16*)(ws + 0 * MB);   // 8 MB; reused as ctx after QKV GEMM
  __hip_bfloat16* wtq = (__hip_bfloat16*)(ws + 8 * MB);
  __hip_bfloat16* wtk = (__hip_bfloat16*)(ws + 10 * MB);
  __hip_bfloat16* wtv = (__hip_bfloat16*)(ws + 12 * MB);
  __hip_bfloat16* wto = (__hip_bfloat16*)(ws + 14 * MB);
  __hip_bfloat16* qb  = (__hip_bfloat16*)(ws + 16 * MB);
  __hip_bfloat16* kb  = (__hip_bfloat16*)(ws + 24 * MB);
  __hip_bfloat16* vt  = (__hip_bfloat16*)(ws + 32 * MB);
  __hip_bfloat16* ctx = xb;  // alias: x no longer needed after QKV projection

  prep_kernel<<<dim3(32, 32, 5), dim3(32, 8), 0, stream>>>(x, xb, Wq, Wk, Wv, Wo,
                                                           wtq, wtk, wtv, wto);
  gemm_kernel<0><<<dim3(8, 3, 32), 256, 0, stream>>>(xb, wtq, wtk, wtv, bq, bk, bv,
                                                     (void*)qb, (void*)kb, (void*)vt);
  attn_kernel<<<dim3(32, 32), 256, 0, stream>>>(qb, kb, vt, ctx);
  gemm_kernel<1><<<dim3(8, 1, 64), 256, 0, stream>>>(ctx, wto, wto, wto, bo, bo, bo,
                                                     d_out, d_out, d_out);
}

// Round 7
// 188.026 us; speedup vs baseline: 1.3830x; 1.3830x over previous
//
#include <hip/hip_runtime.h>
#include <hip/hip_bf16.h>

typedef __attribute__((ext_vector_type(8))) short short8;
typedef __attribute__((ext_vector_type(4))) float floatx4;
typedef __attribute__((ext_vector_type(4))) int intx4;
typedef __attribute__((ext_vector_type(2))) int intx2;

#define D_MODEL 1024
#define SEQ     2048
#define NB      2
#define NH      16
#define HD      64
#define MROWS   4096   // NB*SEQ
#define CZ      (0.125f * 1.44269504f)   // 1/sqrt(64) * log2(e)

__device__ __forceinline__ floatx4 mfma_bf16(short8 a, short8 b, floatx4 c) {
  return __builtin_amdgcn_mfma_f32_16x16x32_bf16(a, b, c, 0, 0, 0);
}

// async global -> LDS, 16 B per lane. LDS dest = wave-uniform base + lane*16.
__device__ __forceinline__ void dma16(const __hip_bfloat16* g, __hip_bfloat16* l) {
  __builtin_amdgcn_global_load_lds(
      (const __attribute__((address_space(1))) void*)g,
      (__attribute__((address_space(3))) void*)l, 16, 0, 0);
}
#define WAIT_VM(n)  __asm__ __volatile__("s_waitcnt vmcnt(" #n ")" ::: "memory")
#define BARRIER()   __asm__ __volatile__("s_barrier" ::: "memory")
#define WAIT_LGKM() __asm__ __volatile__("s_waitcnt lgkmcnt(0)" ::: "memory")

// round-half-up bf16 pair pack (used by GEMM epilogues)
__device__ __forceinline__ int pack2bf(float a, float b) {
  unsigned ua = __builtin_bit_cast(unsigned, a) + 0x8000u;
  unsigned ub = __builtin_bit_cast(unsigned, b) + 0x8000u;
  return (int)__builtin_amdgcn_perm(ub, ua, 0x07060302u);
}

// single-instruction bf16 pair pack (RNE): dst.lo = bf16(a), dst.hi = bf16(b)
__device__ __forceinline__ int cvtpk(float a, float b) {
  int r;
  __asm__("v_cvt_pk_bf16_f32 %0, %1, %2" : "=v"(r) : "v"(a), "v"(b));
  return r;
}

// ---------------- prep: W transpose (z<4) + x fp32->bf16 (z==4) ----------------
__global__ void prep_kernel(const float* __restrict__ x, __hip_bfloat16* __restrict__ xb,
                            const float* __restrict__ W0, const float* __restrict__ W1,
                            const float* __restrict__ W2, const float* __restrict__ W3,
                            __hip_bfloat16* __restrict__ T0, __hip_bfloat16* __restrict__ T1,
                            __hip_bfloat16* __restrict__ T2, __hip_bfloat16* __restrict__ T3) {
  const int z = blockIdx.z;
  if (z == 4) {
    const int tid = threadIdx.y * 32 + threadIdx.x;
    const int base = ((blockIdx.y * 32 + blockIdx.x) * 256 + tid) * 16;
#pragma unroll
    for (int c = 0; c < 4; c++) {
      float4 v = *(const float4*)(x + base + c * 4);
      __hip_bfloat16 tmp[4];
      tmp[0] = __float2bfloat16(v.x);
      tmp[1] = __float2bfloat16(v.y);
      tmp[2] = __float2bfloat16(v.z);
      tmp[3] = __float2bfloat16(v.w);
      *(ushort4*)(xb + base + c * 4) = *(ushort4*)tmp;
    }
    return;
  }
  const float* W = (z == 0) ? W0 : (z == 1) ? W1 : (z == 2) ? W2 : W3;
  __hip_bfloat16* Wt = (z == 0) ? T0 : (z == 1) ? T1 : (z == 2) ? T2 : T3;
  __shared__ float tile[32][33];
  int k0 = blockIdx.x * 32, n0 = blockIdx.y * 32;
  int tx = threadIdx.x, ty = threadIdx.y;  // block (32,8)
#pragma unroll
  for (int i = 0; i < 4; i++)
    tile[ty + 8 * i][tx] = W[(size_t)(k0 + ty + 8 * i) * D_MODEL + n0 + tx];
  __syncthreads();
#pragma unroll
  for (int i = 0; i < 4; i++)
    Wt[(size_t)(n0 + ty + 8 * i) * D_MODEL + k0 + tx] = __float2bfloat16(tile[tx][ty + 8 * i]);
}

// ---------------- GEMM: Y = (X @ W + b) * scale ----------------
// Triple-buffered LDS staging with depth-2 prefetch + counted vmcnt + granule
// XOR-swizzle (phys_granule = logical ^ ((row>>1)&3)): linear LDS dest,
// inverse-swizzled GLOBAL source, swizzled read column.
// XCD-L2 remap: dispatch-linear id lin -> (n, z, m) = (lin/96, (lin%96)/32, lin%32)
// so the 8 n-blocks sharing an X-tile have identical lin%8 -> same XCD -> one L2
// fetch of each 256 KB X-tile instead of 8 (FETCH_SIZE 36 MB -> ~ideal). Bijective:
// 768 = 8*96 (MODE 0), 512 = 8*64 (MODE 1).
// MODE 0: MT=128; grid (8,3,32). z=0 -> Q bf16 [bh][s][d] * CZ;
//         z=1 -> K bf16 [bh][s][d]; z=2 -> V^T bf16 [bh][d][s].
// MODE 1: MT=64; grid (8,1,64). fp32 row-major out.
template <int MODE>
__global__ __launch_bounds__(256) void gemm_kernel(
    const __hip_bfloat16* __restrict__ X,
    const __hip_bfloat16* __restrict__ Wt0, const __hip_bfloat16* __restrict__ Wt1,
    const __hip_bfloat16* __restrict__ Wt2,
    const float* __restrict__ b0, const float* __restrict__ b1, const float* __restrict__ b2,
    void* __restrict__ out0, void* __restrict__ out1, void* __restrict__ out2) {
  constexpr int MT = (MODE == 0) ? 128 : 64;
  constexpr int I = MT / 32;
  constexpr int NKT = D_MODEL / 32;
  constexpr int STAGE_BYTES = 3 * (MT * 32 + 128 * 32) * 2;
  constexpr int EPI_BYTES = 64 * 132 * 4;
  constexpr int SMEM_BYTES = (STAGE_BYTES > EPI_BYTES) ? STAGE_BYTES : EPI_BYTES;

  // XCD-aware role remap from dispatch-linear block id (x fastest).
  int n_idx, z, m_idx;
  if constexpr (MODE == 0) {
    const int lin = blockIdx.x + 8 * (blockIdx.y + 3 * blockIdx.z);  // 0..767
    n_idx = lin / 96;
    const int rem = lin - n_idx * 96;   // rem%8 fixed across n for same (z,m)
    z = rem >> 5;
    m_idx = rem & 31;
  } else {
    const int lin = blockIdx.x + 8 * blockIdx.z;  // 0..511 (grid y == 1)
    n_idx = lin >> 6;
    z = 0;
    m_idx = lin & 63;
  }

  const __hip_bfloat16* Wt = (z == 0) ? Wt0 : (z == 1) ? Wt1 : Wt2;
  const float* bias = (z == 0) ? b0 : (z == 1) ? b1 : b2;
  void* outp = (z == 0) ? out0 : (z == 1) ? out1 : out2;
  const float scale = (MODE == 0 && z == 0) ? CZ : 1.f;

  __shared__ __attribute__((aligned(16))) char smem[SMEM_BYTES];
  __hip_bfloat16* As = (__hip_bfloat16*)smem;                       // 3 bufs of MT*32
  __hip_bfloat16* Bs = (__hip_bfloat16*)smem + 3 * MT * 32;         // 3 bufs of 128*32
  float* Es = (float*)smem;                                         // epilogue scratch

  const int n0 = n_idx * 128;
  const int m0 = m_idx * MT;
  const int t = threadIdx.x;
  const int lane = t & 63, w = t >> 6;
  const int wm = (w >> 1) * (MT / 2), wn = (w & 1) * 64;
  const int lr = lane & 15;
  const int lq = lane >> 4;

  const __hip_bfloat16* Xp = X + (size_t)m0 * D_MODEL;
  const __hip_bfloat16* Wp = Wt + (size_t)n0 * D_MODEL;

  const int lrow = lane >> 2;
  // inverse-swizzled source granule: LDS slot (lane&3) of row lrow receives
  // logical granule (lane&3) ^ ((lrow>>1)&3)
  const int skg = (((lane & 3) ^ ((lane >> 3) & 3)) << 3);
  const int srowA = ((MT == 128) ? (w << 5) : (w << 4)) + lrow;
  const int sbA0 = (((MT == 128) ? (w << 5) : (w << 4)) << 5);
  const int sbA1 = sbA0 + (16 << 5);
  const int srowB = (w << 5) + lrow;
  const int sbB0 = ((w << 5) << 5);
  const int sbB1 = sbB0 + (16 << 5);

#define STAGE_G(kt_, buf_)                                                              \
  {                                                                                     \
    const int kn_ = (kt_) * 32;                                                         \
    __hip_bfloat16* A_ = As + (buf_) * (MT * 32);                                       \
    __hip_bfloat16* B_ = Bs + (buf_) * (128 * 32);                                      \
    dma16(Xp + (size_t)srowA * D_MODEL + kn_ + skg, A_ + sbA0);                         \
    if (MT == 128) dma16(Xp + (size_t)(srowA + 16) * D_MODEL + kn_ + skg, A_ + sbA1);   \
    dma16(Wp + (size_t)srowB * D_MODEL + kn_ + skg, B_ + sbB0);                         \
    dma16(Wp + (size_t)(srowB + 16) * D_MODEL + kn_ + skg, B_ + sbB1);                  \
  }

  floatx4 acc[I][4];
#pragma unroll
  for (int i = 0; i < I; i++)
#pragma unroll
    for (int j = 0; j < 4; j++) acc[i][j] = (floatx4){0.f, 0.f, 0.f, 0.f};

  STAGE_G(0, 0);
  STAGE_G(1, 1);

  // swizzled read column (logical granule lq of row ...+lr lives at slot lq^((lr>>1)&3))
  const int rcol = ((lq ^ ((lr >> 1) & 3)) << 3);

  int cb = 0;
  for (int kt = 0; kt < NKT; kt++) {
    if (kt < NKT - 1) {
      if constexpr (MODE == 0) WAIT_VM(4);
      else                     WAIT_VM(3);
    } else {
      WAIT_VM(0);
    }
    BARRIER();
    if (kt + 2 < NKT) {
      const int nb = (cb == 0) ? 2 : cb - 1;
      STAGE_G(kt + 2, nb);
    }
    const __hip_bfloat16* Ac = As + cb * (MT * 32);
    const __hip_bfloat16* Bc = Bs + cb * (128 * 32);
    short8 af[I], bfr[4];
#pragma unroll
    for (int i = 0; i < I; i++) af[i] = *(const short8*)&Ac[(wm + i * 16 + lr) * 32 + rcol];
#pragma unroll
    for (int j = 0; j < 4; j++) bfr[j] = *(const short8*)&Bc[(wn + j * 16 + lr) * 32 + rcol];
#pragma unroll
    for (int i = 0; i < I; i++)
#pragma unroll
      for (int j = 0; j < 4; j++) acc[i][j] = mfma_bf16(af[i], bfr[j], acc[i][j]);
    cb = (cb == 2) ? 0 : cb + 1;
  }
#undef STAGE_G

  // ---- epilogue via LDS round-trip (staging buffers are free now) ----
  float bvj[4];
#pragma unroll
  for (int j = 0; j < 4; j++) bvj[j] = bias[n0 + wn + j * 16 + lr];

  if constexpr (MODE == 1) {
    // fp32 row-major out. Scratch [64 m][132].
    BARRIER();
#pragma unroll
    for (int i = 0; i < I; i++) {
      const int rowb = wm + i * 16 + lq * 4;
#pragma unroll
      for (int j = 0; j < 4; j++)
#pragma unroll
        for (int r = 0; r < 4; r++)
          Es[(rowb + r) * 132 + wn + j * 16 + lr] = acc[i][j][r] + bvj[j];
    }
    WAIT_LGKM();
    BARRIER();
    const int L = t >> 2, nseg = (t & 3) * 32;
    float* op = (float*)outp + (size_t)(m0 + L) * D_MODEL + n0 + nseg;
    const float* src = &Es[L * 132 + nseg];
#pragma unroll
    for (int k = 0; k < 8; k++) *(float4*)(op + 4 * k) = *(const float4*)(src + 4 * k);
  } else if (z != 2) {
    // Q/K bf16 [bh][s][d]. Two chunks of i in {2c, 2c+1}; scratch [64 m][132].
    for (int c = 0; c < 2; c++) {
      BARRIER();
#pragma unroll
      for (int i2 = 0; i2 < 2; i2++) {
        const int i = 2 * c + i2;
        const int rowb = (w >> 1) * 32 + i2 * 16 + lq * 4;
#pragma unroll
        for (int j = 0; j < 4; j++)
#pragma unroll
          for (int r = 0; r < 4; r++)
            Es[(rowb + r) * 132 + wn + j * 16 + lr] = (acc[i][j][r] + bvj[j]) * scale;
      }
      WAIT_LGKM();
      BARRIER();
      const int L = t >> 2, nseg = (t & 3) * 32;
      const int m = m0 + ((L >> 5) << 6) + (c << 5) + (L & 31);
      const int bb = m >> 11, s = m & 2047;
      const int nn = n0 + nseg;
      __hip_bfloat16* op = (__hip_bfloat16*)outp +
          (((size_t)(bb * NH + (nn >> 6)) * SEQ + s) * HD + (nn & 63));
      const float* src = &Es[L * 132 + nseg];
#pragma unroll
      for (int k = 0; k < 4; k++) {
        intx4 pk;
        pk[0] = pack2bf(src[8 * k + 0], src[8 * k + 1]);
        pk[1] = pack2bf(src[8 * k + 2], src[8 * k + 3]);
        pk[2] = pack2bf(src[8 * k + 4], src[8 * k + 5]);
        pk[3] = pack2bf(src[8 * k + 6], src[8 * k + 7]);
        *(intx4*)(op + 8 * k) = pk;
      }
    }
  } else {
    // V^T bf16 [bh][d][s]. Two chunks of j in {2c, 2c+1}; scratch [64 n][132 m].
    for (int c = 0; c < 2; c++) {
      BARRIER();
#pragma unroll
      for (int j2 = 0; j2 < 2; j2++) {
        const int j = 2 * c + j2;
        const int nl = ((w & 1) << 5) + (j2 << 4) + lr;
#pragma unroll
        for (int i = 0; i < I; i++) {
          const int moff = (w >> 1) * 64 + i * 16 + lq * 4;
          floatx4 v = acc[i][j];
          v[0] += bvj[j]; v[1] += bvj[j]; v[2] += bvj[j]; v[3] += bvj[j];
          *(floatx4*)&Es[nl * 132 + moff] = v;
        }
      }
      WAIT_LGKM();
      BARRIER();
      const int nl = t >> 2, mseg = (t & 3) * 32;
      const int n = n0 + ((nl >> 5) << 6) + (c << 5) + (nl & 31);
      const int s0 = m0 & 2047, bb = m0 >> 11;
      __hip_bfloat16* op = (__hip_bfloat16*)outp +
          (((size_t)(bb * NH + (n >> 6)) * HD + (n & 63)) * SEQ + s0 + mseg);
      const float* src = &Es[nl * 132 + mseg];
#pragma unroll
      for (int k = 0; k < 4; k++) {
        intx4 pk;
        pk[0] = pack2bf(src[8 * k + 0], src[8 * k + 1]);
        pk[1] = pack2bf(src[8 * k + 2], src[8 * k + 3]);
        pk[2] = pack2bf(src[8 * k + 4], src[8 * k + 5]);
        pk[3] = pack2bf(src[8 * k + 6], src[8 * k + 7]);
        *(intx4*)(op + 8 * k) = pk;
      }
    }
  }
}

// ---------------- flash attention, causal, no-max softmax, occupancy-first ----------------
// PROVEN VERSION (R1-R3, 45.0-45.2 us, passed 3x) -- reverted verbatim after the
// R4/R5/R6 restructure attempts regressed or broke.
// Grid (32 bh, 32 qt), qt = 31-blockIdx.y (largest first -> backfill balances
// triangular work). Linear block id = bh + 32*qy -> XCD = bh%8: all qt-blocks of a
// bh share one XCD; its 512 KB K/V stays L2-local (already optimal, left as-is).
// Block 256 thr = 4 waves: wr = w&1 (32-q half of 64-row tile), wb = w>>1
// (interleaved 16-key groups of a 64-key tile). LDS 32 KB -> 4 blocks/CU.
// S^T orientation. ZERO-SHUFFLE PV: kappa-permuted K-ordering makes the S^T output
// registers the PV B-frag after cvt_pk packing; V^T read as 2x ds_read_b64 per dt.
// Row-sums via ones-vector MFMA into lsacc.
__global__ __launch_bounds__(256, 4) void attn_kernel(
    const __hip_bfloat16* __restrict__ Q, const __hip_bfloat16* __restrict__ Kg,
    const __hip_bfloat16* __restrict__ Vt, __hip_bfloat16* __restrict__ ctx) {
  const int bh = blockIdx.x;
  const int b = bh >> 4, h = bh & 15;
  const int qt = 31 - blockIdx.y;
  const int t = threadIdx.x, lane = t & 63, w = t >> 6;
  const int lr = lane & 15, lq = lane >> 4;
  const int wr = w & 1, wb = w >> 1;

  __shared__ __attribute__((aligned(16))) __hip_bfloat16 Ks[2][64 * 64];   // 8 KB each
  __shared__ __attribute__((aligned(16))) __hip_bfloat16 VTs[2][64 * 64];  // 8 KB each

  const __hip_bfloat16* Qb = Q + (size_t)bh * SEQ * HD;
  const __hip_bfloat16* Kb = Kg + (size_t)bh * SEQ * HD;
  const __hip_bfloat16* Vb = Vt + (size_t)bh * HD * SEQ;

  const int qrow0 = qt * 64 + wr * 32;  // this wave's first query row

  // Q fragments (before any DMA -> clean vmcnt accounting)
  short8 qf[2][2];  // [rt][ks]
#pragma unroll
  for (int rt = 0; rt < 2; rt++)
#pragma unroll
    for (int ks = 0; ks < 2; ks++)
      qf[rt][ks] = *(const short8*)(Qb + (size_t)(qrow0 + rt * 16 + lr) * HD + ks * 32 + lq * 8);

  // staging constants: both tiles are 64 rows x 64 elems (128 B row, 8 granules, swz3)
  const int srow = (w << 4) + (lane >> 3);  // rows srow, srow+8
  const int sgl = lane & 7;
  const int sb0 = (w << 4) << 6;
  const int sb1 = ((w << 4) + 8) << 6;

#define STAGE(tb, nb)                                                                  \
  {                                                                                    \
    const int r0 = srow, r1 = srow + 8;                                                \
    dma16(Kb + ((size_t)((tb) + r0) << 6) + ((sgl ^ (r0 & 7)) << 3), &Ks[nb][sb0]);    \
    dma16(Kb + ((size_t)((tb) + r1) << 6) + ((sgl ^ (r1 & 7)) << 3), &Ks[nb][sb1]);    \
    dma16(Vb + (size_t)r0 * SEQ + (tb) + ((sgl ^ (r0 & 7)) << 3), &VTs[nb][sb0]);      \
    dma16(Vb + (size_t)r1 * SEQ + (tb) + ((sgl ^ (r1 & 7)) << 3), &VTs[nb][sb1]);      \
  }

  const int nkt = qt + 1;
  STAGE(0, 0);

  floatx4 o[2][4];
#pragma unroll
  for (int rt = 0; rt < 2; rt++)
#pragma unroll
    for (int dt = 0; dt < 4; dt++) o[rt][dt] = (floatx4){0.f, 0.f, 0.f, 0.f};
  floatx4 lsacc[2];
  lsacc[0] = (floatx4){0.f, 0.f, 0.f, 0.f};
  lsacc[1] = (floatx4){0.f, 0.f, 0.f, 0.f};

  short8 ones;
#pragma unroll
  for (int j = 0; j < 8; j++) ones[j] = (short)0x3F80;  // bf16 1.0

  // LDS read offsets (element units)
  const int kfb0 = ((wb << 4) + lr) << 6;                  // + nt*2048
  const int kg0 = ((lq ^ (lr & 7)) << 3);                  // ks=0 granule
  const int kg1 = (((4 + lq) ^ (lr & 7)) << 3);            // ks=1
  // V^T permuted-K reads: keys {wb*16+lq*4+c} (j=0..3) and {32+wb*16+lq*4+c} (j=4..7)
  const int vga = (((wb * 2 + (lq >> 1)) ^ (lr & 7)) << 3) + ((lq & 1) << 2);
  const int vgb = (((4 + wb * 2 + (lq >> 1)) ^ (lr & 7)) << 3) + ((lq & 1) << 2);

  for (int kt = 0; kt < nkt; kt++) {
    WAIT_VM(0);
    BARRIER();
    if (kt + 1 < nkt) STAGE((kt + 1) << 6, (kt + 1) & 1);

    const int kw0 = (kt << 6) + (wb << 4);  // wave's first key
    if (kw0 <= qrow0 + 31) {
      const __hip_bfloat16* Kc = Ks[kt & 1];
      const __hip_bfloat16* Vc = VTs[kt & 1];

      // K frags (shared across rt): row = nt*32 + wb*16 + lr
      short8 kf[2][2];  // [ks][nt]
#pragma unroll
      for (int nt = 0; nt < 2; nt++) {
        kf[0][nt] = *(const short8*)&Kc[(nt << 11) + kfb0 + kg0];
        kf[1][nt] = *(const short8*)&Kc[(nt << 11) + kfb0 + kg1];
      }
      // S^T = K Q^T
      floatx4 s[2][2];  // [rt][nt]
#pragma unroll
      for (int rt = 0; rt < 2; rt++)
#pragma unroll
        for (int nt = 0; nt < 2; nt++) s[rt][nt] = (floatx4){0.f, 0.f, 0.f, 0.f};
#pragma unroll
      for (int ks = 0; ks < 2; ks++)
#pragma unroll
        for (int nt = 0; nt < 2; nt++) {
          s[0][nt] = mfma_bf16(kf[ks][nt], qf[0][ks], s[0][nt]);
          s[1][nt] = mfma_bf16(kf[ks][nt], qf[1][ks], s[1][nt]);
        }

      // numerators (mask only near the diagonal) -> bf16 pairs, direct PV B-frag
      const bool need_mask = (kw0 + 47 > qrow0);
      short8 pf[2];
#pragma unroll
      for (int rt = 0; rt < 2; rt++) {
        const int q = qrow0 + rt * 16 + lr;
        intx4 pk;
#pragma unroll
        for (int nt = 0; nt < 2; nt++) {
          const int kbase = (kt << 6) + (nt << 5) + (wb << 4) + (lq << 2);
          float x0 = s[rt][nt][0], x1 = s[rt][nt][1], x2 = s[rt][nt][2], x3 = s[rt][nt][3];
          if (need_mask) {
            x0 = (kbase + 0 <= q) ? x0 : -1e30f;
            x1 = (kbase + 1 <= q) ? x1 : -1e30f;
            x2 = (kbase + 2 <= q) ? x2 : -1e30f;
            x3 = (kbase + 3 <= q) ? x3 : -1e30f;
          }
          const float p0 = __builtin_amdgcn_exp2f(x0);
          const float p1 = __builtin_amdgcn_exp2f(x1);
          const float p2 = __builtin_amdgcn_exp2f(x2);
          const float p3 = __builtin_amdgcn_exp2f(x3);
          pk[2 * nt + 0] = cvtpk(p0, p1);
          pk[2 * nt + 1] = cvtpk(p2, p3);
        }
        pf[rt] = __builtin_bit_cast(short8, pk);
      }

      // row-sums on the MFMA pipe: every output reg = sum_k P^T[k][q]
      lsacc[0] = mfma_bf16(ones, pf[0], lsacc[0]);
      lsacc[1] = mfma_bf16(ones, pf[1], lsacc[1]);

      // O^T += V^T P^T with permuted K-ordering: two b64 reads per dt land
      // directly in the A-frag register pairs (no cross-lane shuffles).
#pragma unroll
      for (int dt = 0; dt < 4; dt++) {
        const int rb = ((dt << 4) + lr) << 6;
        intx4 vi;
        *(intx2*)&vi = *(const intx2*)&Vc[rb + vga];
        *(((intx2*)&vi) + 1) = *(const intx2*)&Vc[rb + vgb];
        short8 vf = __builtin_bit_cast(short8, vi);
        o[0][dt] = mfma_bf16(vf, pf[0], o[0][dt]);
        o[1][dt] = mfma_bf16(vf, pf[1], o[1][dt]);
      }
    }
  }

  // ---- epilogue: merge wb partials via (now free) LDS buffers ----
  BARRIER();
  if (wb == 1) {
    float* d0 = (float*)&Ks[0][0];   // rt0 partials (8 KB)
    float* d1 = (float*)&Ks[1][0];   // rt1 partials (8 KB)
    float* dl = (float*)&VTs[0][0];  // l partials
    const int base = (wr << 10) + (lane << 4);
#pragma unroll
    for (int dt = 0; dt < 4; dt++) *(floatx4*)&d0[base + (dt << 2)] = o[0][dt];
#pragma unroll
    for (int dt = 0; dt < 4; dt++) *(floatx4*)&d1[base + (dt << 2)] = o[1][dt];
    dl[(wr << 7) + (lane << 1)] = lsacc[0][0];
    dl[(wr << 7) + (lane << 1) + 1] = lsacc[1][0];
    WAIT_LGKM();
  }
  BARRIER();
  if (wb == 0) {
    const float* d0 = (const float*)&Ks[0][0];
    const float* d1 = (const float*)&Ks[1][0];
    const float* dl = (const float*)&VTs[0][0];
    const int base = (wr << 10) + (lane << 4);
#pragma unroll
    for (int dt = 0; dt < 4; dt++) {
      o[0][dt] += *(const floatx4*)&d0[base + (dt << 2)];
      o[1][dt] += *(const floatx4*)&d1[base + (dt << 2)];
    }
    // lsacc already holds the full 32-key wave sum in every reg (ones-MFMA),
    // so no cross-lane reduction is needed -- just merge the other wb half.
    float inv[2];
    inv[0] = 1.f / (lsacc[0][0] + dl[(wr << 7) + (lane << 1)]);
    inv[1] = 1.f / (lsacc[1][0] + dl[(wr << 7) + (lane << 1) + 1]);
#pragma unroll
    for (int rt = 0; rt < 2; rt++) {
      const int row = qrow0 + rt * 16 + lr;
      __hip_bfloat16* cp = ctx + (size_t)b * SEQ * D_MODEL + (size_t)row * D_MODEL + h * HD;
#pragma unroll
      for (int dt = 0; dt < 4; dt++) {
        ushort4 pk;
        __hip_bfloat16* pp = (__hip_bfloat16*)&pk;
#pragma unroll
        for (int r = 0; r < 4; r++) pp[r] = __float2bfloat16(o[rt][dt][r] * inv[rt]);
        *(ushort4*)(cp + (dt << 4) + (lq << 2)) = pk;
      }
    }
  }
#undef STAGE
}

extern "C" void kernel_launch(void* const* d_in, const int* in_sizes, int n_in,
                              void* d_out, int out_size, void* d_ws, size_t ws_size,
                              hipStream_t stream) {
  const float* x  = (const float*)d_in[0];
  const float* Wq = (const float*)d_in[1];
  const float* bq = (const float*)d_in[2];
  const float* Wk = (const float*)d_in[3];
  const float* bk = (const float*)d_in[4];
  const float* Wv = (const float*)d_in[5];
  const float* bv = (const float*)d_in[6];
  const float* Wo = (const float*)d_in[7];
  const float* bo = (const float*)d_in[8];

  char* ws = (char*)d_ws;
  const size_t MB = 1u << 20;
  __hip_bfloat16* xb  = (__hip_bfloat16*)(ws + 0 * MB);   // 8 MB; reused as ctx after QKV GEMM
  __hip_bfloat16* wtq = (__hip_bfloat16*)(ws + 8 * MB);
  __hip_bfloat16* wtk = (__hip_bfloat16*)(ws + 10 * MB);
  __hip_bfloat16* wtv = (__hip_bfloat16*)(ws + 12 * MB);
  __hip_bfloat16* wto = (__hip_bfloat16*)(ws + 14 * MB);
  __hip_bfloat16* qb  = (__hip_bfloat16*)(ws + 16 * MB);
  __hip_bfloat16* kb  = (__hip_bfloat16*)(ws + 24 * MB);
  __hip_bfloat16* vt  = (__hip_bfloat16*)(ws + 32 * MB);
  __hip_bfloat16* ctx = xb;  // alias: x no longer needed after QKV projection

  prep_kernel<<<dim3(32, 32, 5), dim3(32, 8), 0, stream>>>(x, xb, Wq, Wk, Wv, Wo,
                                                           wtq, wtk, wtv, wto);
  gemm_kernel<0><<<dim3(8, 3, 32), 256, 0, stream>>>(xb, wtq, wtk, wtv, bq, bk, bv,
                                                     (void*)qb, (void*)kb, (void*)vt);
  attn_kernel<<<dim3(32, 32), 256, 0, stream>>>(qb, kb, vt, ctx);
  gemm_kernel<1><<<dim3(8, 1, 64), 256, 0, stream>>>(ctx, wto, wto, wto, bo, bo, bo,
                                                     d_out, d_out, d_out);
}

// Round 8
// 186.616 us; speedup vs baseline: 1.3934x; 1.0076x over previous
//
#include <hip/hip_runtime.h>
#include <hip/hip_bf16.h>

typedef __attribute__((ext_vector_type(8))) short short8;
typedef __attribute__((ext_vector_type(4))) float floatx4;
typedef __attribute__((ext_vector_type(4))) int intx4;
typedef __attribute__((ext_vector_type(2))) int intx2;

#define D_MODEL 1024
#define SEQ     2048
#define NB      2
#define NH      16
#define HD      64
#define MROWS   4096   // NB*SEQ
#define CZ      (0.125f * 1.44269504f)   // 1/sqrt(64) * log2(e)

__device__ __forceinline__ floatx4 mfma_bf16(short8 a, short8 b, floatx4 c) {
  return __builtin_amdgcn_mfma_f32_16x16x32_bf16(a, b, c, 0, 0, 0);
}

// async global -> LDS, 16 B per lane. LDS dest = wave-uniform base + lane*16.
__device__ __forceinline__ void dma16(const __hip_bfloat16* g, __hip_bfloat16* l) {
  __builtin_amdgcn_global_load_lds(
      (const __attribute__((address_space(1))) void*)g,
      (__attribute__((address_space(3))) void*)l, 16, 0, 0);
}
#define WAIT_VM(n)  __asm__ __volatile__("s_waitcnt vmcnt(" #n ")" ::: "memory")
#define BARRIER()   __asm__ __volatile__("s_barrier" ::: "memory")
#define WAIT_LGKM() __asm__ __volatile__("s_waitcnt lgkmcnt(0)" ::: "memory")

// round-half-up bf16 pair pack (used by GEMM epilogues)
__device__ __forceinline__ int pack2bf(float a, float b) {
  unsigned ua = __builtin_bit_cast(unsigned, a) + 0x8000u;
  unsigned ub = __builtin_bit_cast(unsigned, b) + 0x8000u;
  return (int)__builtin_amdgcn_perm(ub, ua, 0x07060302u);
}

// single-instruction bf16 pair pack (RNE): dst.lo = bf16(a), dst.hi = bf16(b)
__device__ __forceinline__ int cvtpk(float a, float b) {
  int r;
  __asm__("v_cvt_pk_bf16_f32 %0, %1, %2" : "=v"(r) : "v"(a), "v"(b));
  return r;
}

// ---------------- prep: W transpose (z<4) + x fp32->bf16 (z==4) ----------------
__global__ void prep_kernel(const float* __restrict__ x, __hip_bfloat16* __restrict__ xb,
                            const float* __restrict__ W0, const float* __restrict__ W1,
                            const float* __restrict__ W2, const float* __restrict__ W3,
                            __hip_bfloat16* __restrict__ T0, __hip_bfloat16* __restrict__ T1,
                            __hip_bfloat16* __restrict__ T2, __hip_bfloat16* __restrict__ T3) {
  const int z = blockIdx.z;
  if (z == 4) {
    const int tid = threadIdx.y * 32 + threadIdx.x;
    const int base = ((blockIdx.y * 32 + blockIdx.x) * 256 + tid) * 16;
#pragma unroll
    for (int c = 0; c < 4; c++) {
      float4 v = *(const float4*)(x + base + c * 4);
      __hip_bfloat16 tmp[4];
      tmp[0] = __float2bfloat16(v.x);
      tmp[1] = __float2bfloat16(v.y);
      tmp[2] = __float2bfloat16(v.z);
      tmp[3] = __float2bfloat16(v.w);
      *(ushort4*)(xb + base + c * 4) = *(ushort4*)tmp;
    }
    return;
  }
  const float* W = (z == 0) ? W0 : (z == 1) ? W1 : (z == 2) ? W2 : W3;
  __hip_bfloat16* Wt = (z == 0) ? T0 : (z == 1) ? T1 : (z == 2) ? T2 : T3;
  __shared__ float tile[32][33];
  int k0 = blockIdx.x * 32, n0 = blockIdx.y * 32;
  int tx = threadIdx.x, ty = threadIdx.y;  // block (32,8)
#pragma unroll
  for (int i = 0; i < 4; i++)
    tile[ty + 8 * i][tx] = W[(size_t)(k0 + ty + 8 * i) * D_MODEL + n0 + tx];
  __syncthreads();
#pragma unroll
  for (int i = 0; i < 4; i++)
    Wt[(size_t)(n0 + ty + 8 * i) * D_MODEL + k0 + tx] = __float2bfloat16(tile[tx][ty + 8 * i]);
}

// ---------------- QKV GEMM: 256x256 tile, 8-phase counted-vmcnt schedule ----------------
// Port of the m201 8-phase template. 512 thr = 8 waves (2M x 4N); wave owns 128x64
// (acc[8][4]); BK=64; LDS = 2dbuf x (A 32K + B 32K) = 128 KB -> 1 block/CU.
// Both tiles stored [256 rows][64 cols] bf16 (128B rows) with the in-session-proven
// granule swizzle phys_g = g ^ (row&7): linear LDS dest (dma16 requirement),
// inverse-swizzled GLOBAL source, swizzled ds_read column.
// Per K-step: 4 phases; phase p = {issue 2 stage-dma16 for kt+1, ds_read i-quadrant
// {2p,2p+1} (+ all B frags in ph0), setprio(1), 16 MFMA, setprio(0), barrier}.
// Counted waits (FIFO-derived, never 0 mid-loop): stage order per K-step is
// [B0 B1 | B2 B3 | Au0 Au2 | Au1 Au3]; ph0 needs all but Au1,Au3 -> vmcnt(2);
// ph2 needs Au1,Au3, with 4 newer B-loads of kt+1 in flight -> vmcnt(4).
// grid (4 n, 3 z, 16 m). z=0 -> Q bf16 [bh][s][d]*CZ; z=1 -> K; z=2 -> V^T [bh][d][s].
__global__ __launch_bounds__(512, 2) void gemm256_kernel(
    const __hip_bfloat16* __restrict__ X,
    const __hip_bfloat16* __restrict__ Wt0, const __hip_bfloat16* __restrict__ Wt1,
    const __hip_bfloat16* __restrict__ Wt2,
    const float* __restrict__ b0, const float* __restrict__ b1, const float* __restrict__ b2,
    void* __restrict__ out0, void* __restrict__ out1, void* __restrict__ out2) {
  constexpr int NKT = D_MODEL / 64;     // 16 K-steps
  constexpr int BUFE = 256 * 64;        // elems per LDS tile buffer

  const int z = blockIdx.y;
  const __hip_bfloat16* Wt = (z == 0) ? Wt0 : (z == 1) ? Wt1 : Wt2;
  const float* bias = (z == 0) ? b0 : (z == 1) ? b1 : b2;
  void* outp = (z == 0) ? out0 : (z == 1) ? out1 : out2;
  const float scale = (z == 0) ? CZ : 1.f;

  __shared__ __attribute__((aligned(16))) char smem[131072];  // 128 KB
  __hip_bfloat16* As = (__hip_bfloat16*)smem;                 // 2 x 32 KB
  __hip_bfloat16* Bs = (__hip_bfloat16*)smem + 2 * BUFE;      // 2 x 32 KB
  float* Es = (float*)smem;                                   // epilogue scratch [64][260]

  const int n0 = blockIdx.x * 256;
  const int m0 = blockIdx.z * 256;
  const int t = threadIdx.x;
  const int lane = t & 63, w = t >> 6;
  const int wm = w >> 2, wn = w & 3;
  const int lr = lane & 15, lq = lane >> 4;

  const __hip_bfloat16* Xp = X + (size_t)m0 * D_MODEL;
  const __hip_bfloat16* Wp = Wt + (size_t)n0 * D_MODEL;

  // staging: one dma16 covers 64 rows (512 thr x 16B = 8 KB). Thread t handles
  // row (t>>3) of the unit, source granule inverse-swizzled.
  const int srow = t >> 3;                    // 0..63
  const int sg = (t & 7) ^ (srow & 7);        // source granule
  const int wbase = (w << 3) << 6;            // wave-uniform LDS elem base (8 rows/wave)

#define STAGE_A8(kt_, u_)                                                             \
  dma16(Xp + (size_t)(((u_) << 6) + srow) * D_MODEL + ((kt_) << 6) + (sg << 3),       \
        As + (((kt_) & 1) ? BUFE : 0) + ((u_) << 12) + wbase)
#define STAGE_B8(kt_, u_)                                                             \
  dma16(Wp + (size_t)(((u_) << 6) + srow) * D_MODEL + ((kt_) << 6) + (sg << 3),       \
        Bs + (((kt_) & 1) ? BUFE : 0) + ((u_) << 12) + wbase)

  floatx4 acc[8][4];
#pragma unroll
  for (int i = 0; i < 8; i++)
#pragma unroll
    for (int j = 0; j < 4; j++) acc[i][j] = (floatx4){0.f, 0.f, 0.f, 0.f};

  // prologue: stage kt=0 in consumption order
  STAGE_B8(0, 0); STAGE_B8(0, 1); STAGE_B8(0, 2); STAGE_B8(0, 3);
  STAGE_A8(0, 0); STAGE_A8(0, 2); STAGE_A8(0, 1); STAGE_A8(0, 3);

#define READ_A2(dst, IB)                                                              \
  _Pragma("unroll") for (int i2 = 0; i2 < 2; i2++) {                                  \
    const int ra = (wm << 7) + (((IB) + i2) << 4) + lr;                               \
    _Pragma("unroll") for (int ks = 0; ks < 2; ks++)                                  \
      dst[i2][ks] = *(const short8*)&Ac[(ra << 6) + ((((ks << 2) + lq) ^ (ra & 7)) << 3)]; \
  }
#define MFMA_Q(IB, afr)                                                               \
  __builtin_amdgcn_s_setprio(1);                                                      \
  _Pragma("unroll") for (int i2 = 0; i2 < 2; i2++)                                    \
  _Pragma("unroll") for (int j = 0; j < 4; j++) {                                     \
    acc[(IB) + i2][j] = mfma_bf16(afr[i2][0], bf[j][0], acc[(IB) + i2][j]);           \
    acc[(IB) + i2][j] = mfma_bf16(afr[i2][1], bf[j][1], acc[(IB) + i2][j]);           \
  }                                                                                   \
  __builtin_amdgcn_s_setprio(0);

  for (int kt = 0; kt < NKT; kt++) {
    const __hip_bfloat16* Ac = As + ((kt & 1) ? BUFE : 0);
    const __hip_bfloat16* Bc = Bs + ((kt & 1) ? BUFE : 0);
    const bool pre = (kt + 1 < NKT);

    // ---- phase 0: B frags + i{0,1} ----
    WAIT_VM(2);
    BARRIER();
    if (pre) { STAGE_B8(kt + 1, 0); STAGE_B8(kt + 1, 1); }
    short8 bf[4][2];
#pragma unroll
    for (int j = 0; j < 4; j++) {
      const int rb = (wn << 6) + (j << 4) + lr;
#pragma unroll
      for (int ks = 0; ks < 2; ks++)
        bf[j][ks] = *(const short8*)&Bc[(rb << 6) + ((((ks << 2) + lq) ^ (rb & 7)) << 3)];
    }
    {
      short8 a0[2][2];
      READ_A2(a0, 0);
      MFMA_Q(0, a0);
    }
    BARRIER();

    // ---- phase 1: i{2,3} ----
    if (pre) { STAGE_B8(kt + 1, 2); STAGE_B8(kt + 1, 3); }
    {
      short8 a1[2][2];
      READ_A2(a1, 2);
      MFMA_Q(2, a1);
    }
    BARRIER();

    // ---- phase 2: i{4,5} (needs Au1,Au3 of this kt) ----
    if (pre) { WAIT_VM(4); } else { WAIT_VM(0); }
    BARRIER();
    if (pre) { STAGE_A8(kt + 1, 0); STAGE_A8(kt + 1, 2); }
    {
      short8 a2[2][2];
      READ_A2(a2, 4);
      MFMA_Q(4, a2);
    }
    BARRIER();

    // ---- phase 3: i{6,7} ----
    if (pre) { STAGE_A8(kt + 1, 1); STAGE_A8(kt + 1, 3); }
    {
      short8 a3[2][2];
      READ_A2(a3, 6);
      MFMA_Q(6, a3);
    }
    BARRIER();
  }
#undef READ_A2
#undef MFMA_Q
#undef STAGE_A8
#undef STAGE_B8

  // ---- epilogue via LDS round-trip, scratch [64 rows][260] floats (~66 KB) ----
  float bvj[4];
#pragma unroll
  for (int j = 0; j < 4; j++) bvj[j] = bias[n0 + (wn << 6) + j * 16 + lr];

  if (z != 2) {
    // Q/K bf16 [bh][s][d]. 4 chunks of 64 rows (i-pairs {2c,2c+1} x both wm).
    for (int c = 0; c < 4; c++) {
      BARRIER();
#pragma unroll
      for (int i2 = 0; i2 < 2; i2++) {
        const int rowl = (wm << 5) + (i2 << 4) + (lq << 2);
#pragma unroll
        for (int j = 0; j < 4; j++)
#pragma unroll
          for (int r = 0; r < 4; r++)
            Es[(rowl + r) * 260 + (wn << 6) + j * 16 + lr] =
                (acc[2 * c + i2][j][r] + bvj[j]) * scale;
      }
      WAIT_LGKM();
      BARRIER();
      const int rl = t >> 3, cs = (t & 7) * 32;
      const int m = m0 + ((rl >> 5) << 7) + (c << 5) + (rl & 31);
      const int bb = m >> 11, s = m & 2047;
      const int n = n0 + cs;
      __hip_bfloat16* op = (__hip_bfloat16*)outp +
          (((size_t)(bb * NH + (n >> 6)) * SEQ + s) * HD + (n & 63));
      const float* src = &Es[rl * 260 + cs];
#pragma unroll
      for (int k = 0; k < 4; k++) {
        intx4 pk;
        pk[0] = pack2bf(src[8 * k + 0], src[8 * k + 1]);
        pk[1] = pack2bf(src[8 * k + 2], src[8 * k + 3]);
        pk[2] = pack2bf(src[8 * k + 4], src[8 * k + 5]);
        pk[3] = pack2bf(src[8 * k + 6], src[8 * k + 7]);
        *(intx4*)(op + 8 * k) = pk;
      }
    }
  } else {
    // V^T bf16 [bh][d][s]. 4 chunks, one j per chunk; scratch [64 n][260 m].
    for (int jj = 0; jj < 4; jj++) {
      BARRIER();
      {
        const int nc = (wn << 4) + lr;
#pragma unroll
        for (int i = 0; i < 8; i++) {
          const int ml = (wm << 7) + (i << 4) + (lq << 2);
          floatx4 v = acc[i][jj];
          v[0] += bvj[jj]; v[1] += bvj[jj]; v[2] += bvj[jj]; v[3] += bvj[jj];
          *(floatx4*)&Es[nc * 260 + ml] = v;
        }
      }
      WAIT_LGKM();
      BARRIER();
      const int nc2 = t >> 3, ms = (t & 7) * 32;
      const int n = n0 + ((nc2 >> 4) << 6) + (jj << 4) + (nc2 & 15);
      const int s0 = m0 & 2047, bb = m0 >> 11;
      __hip_bfloat16* op = (__hip_bfloat16*)outp +
          (((size_t)(bb * NH + (n >> 6)) * HD + (n & 63)) * SEQ + s0 + ms);
      const float* src = &Es[nc2 * 260 + ms];
#pragma unroll
      for (int k = 0; k < 4; k++) {
        intx4 pk;
        pk[0] = pack2bf(src[8 * k + 0], src[8 * k + 1]);
        pk[1] = pack2bf(src[8 * k + 2], src[8 * k + 3]);
        pk[2] = pack2bf(src[8 * k + 4], src[8 * k + 5]);
        pk[3] = pack2bf(src[8 * k + 6], src[8 * k + 7]);
        *(intx4*)(op + 8 * k) = pk;
      }
    }
  }
}

// ---------------- output GEMM (unchanged proven template, MODE 1 only) ----------------
template <int MODE>
__global__ __launch_bounds__(256) void gemm_kernel(
    const __hip_bfloat16* __restrict__ X,
    const __hip_bfloat16* __restrict__ Wt0, const __hip_bfloat16* __restrict__ Wt1,
    const __hip_bfloat16* __restrict__ Wt2,
    const float* __restrict__ b0, const float* __restrict__ b1, const float* __restrict__ b2,
    void* __restrict__ out0, void* __restrict__ out1, void* __restrict__ out2) {
  constexpr int MT = (MODE == 0) ? 128 : 64;
  constexpr int I = MT / 32;
  constexpr int NKT = D_MODEL / 32;
  constexpr int STAGE_BYTES = 3 * (MT * 32 + 128 * 32) * 2;
  constexpr int EPI_BYTES = 64 * 132 * 4;
  constexpr int SMEM_BYTES = (STAGE_BYTES > EPI_BYTES) ? STAGE_BYTES : EPI_BYTES;

  int n_idx, z, m_idx;
  {
    const int lin = blockIdx.x + 8 * blockIdx.z;  // 0..511 (grid y == 1)
    n_idx = lin >> 6;
    z = 0;
    m_idx = lin & 63;
  }

  const __hip_bfloat16* Wt = (z == 0) ? Wt0 : (z == 1) ? Wt1 : Wt2;
  const float* bias = (z == 0) ? b0 : (z == 1) ? b1 : b2;
  void* outp = (z == 0) ? out0 : (z == 1) ? out1 : out2;

  __shared__ __attribute__((aligned(16))) char smem[SMEM_BYTES];
  __hip_bfloat16* As = (__hip_bfloat16*)smem;
  __hip_bfloat16* Bs = (__hip_bfloat16*)smem + 3 * MT * 32;
  float* Es = (float*)smem;

  const int n0 = n_idx * 128;
  const int m0 = m_idx * MT;
  const int t = threadIdx.x;
  const int lane = t & 63, w = t >> 6;
  const int wm = (w >> 1) * (MT / 2), wn = (w & 1) * 64;
  const int lr = lane & 15;
  const int lq = lane >> 4;

  const __hip_bfloat16* Xp = X + (size_t)m0 * D_MODEL;
  const __hip_bfloat16* Wp = Wt + (size_t)n0 * D_MODEL;

  const int lrow = lane >> 2;
  const int skg = (((lane & 3) ^ ((lane >> 3) & 3)) << 3);
  const int srowA = ((MT == 128) ? (w << 5) : (w << 4)) + lrow;
  const int sbA0 = (((MT == 128) ? (w << 5) : (w << 4)) << 5);
  const int sbA1 = sbA0 + (16 << 5);
  const int srowB = (w << 5) + lrow;
  const int sbB0 = ((w << 5) << 5);
  const int sbB1 = sbB0 + (16 << 5);

#define STAGE_G(kt_, buf_)                                                              \
  {                                                                                     \
    const int kn_ = (kt_) * 32;                                                         \
    __hip_bfloat16* A_ = As + (buf_) * (MT * 32);                                       \
    __hip_bfloat16* B_ = Bs + (buf_) * (128 * 32);                                      \
    dma16(Xp + (size_t)srowA * D_MODEL + kn_ + skg, A_ + sbA0);                         \
    if (MT == 128) dma16(Xp + (size_t)(srowA + 16) * D_MODEL + kn_ + skg, A_ + sbA1);   \
    dma16(Wp + (size_t)srowB * D_MODEL + kn_ + skg, B_ + sbB0);                         \
    dma16(Wp + (size_t)(srowB + 16) * D_MODEL + kn_ + skg, B_ + sbB1);                  \
  }

  floatx4 acc[I][4];
#pragma unroll
  for (int i = 0; i < I; i++)
#pragma unroll
    for (int j = 0; j < 4; j++) acc[i][j] = (floatx4){0.f, 0.f, 0.f, 0.f};

  STAGE_G(0, 0);
  STAGE_G(1, 1);

  const int rcol = ((lq ^ ((lr >> 1) & 3)) << 3);

  int cb = 0;
  for (int kt = 0; kt < NKT; kt++) {
    if (kt < NKT - 1) {
      WAIT_VM(3);
    } else {
      WAIT_VM(0);
    }
    BARRIER();
    if (kt + 2 < NKT) {
      const int nb = (cb == 0) ? 2 : cb - 1;
      STAGE_G(kt + 2, nb);
    }
    const __hip_bfloat16* Ac = As + cb * (MT * 32);
    const __hip_bfloat16* Bc = Bs + cb * (128 * 32);
    short8 af[I], bfr[4];
#pragma unroll
    for (int i = 0; i < I; i++) af[i] = *(const short8*)&Ac[(wm + i * 16 + lr) * 32 + rcol];
#pragma unroll
    for (int j = 0; j < 4; j++) bfr[j] = *(const short8*)&Bc[(wn + j * 16 + lr) * 32 + rcol];
#pragma unroll
    for (int i = 0; i < I; i++)
#pragma unroll
      for (int j = 0; j < 4; j++) acc[i][j] = mfma_bf16(af[i], bfr[j], acc[i][j]);
    cb = (cb == 2) ? 0 : cb + 1;
  }
#undef STAGE_G

  float bvj[4];
#pragma unroll
  for (int j = 0; j < 4; j++) bvj[j] = bias[n0 + wn + j * 16 + lr];

  // fp32 row-major out. Scratch [64 m][132].
  BARRIER();
#pragma unroll
  for (int i = 0; i < I; i++) {
    const int rowb = wm + i * 16 + lq * 4;
#pragma unroll
    for (int j = 0; j < 4; j++)
#pragma unroll
      for (int r = 0; r < 4; r++)
        Es[(rowb + r) * 132 + wn + j * 16 + lr] = acc[i][j][r] + bvj[j];
  }
  WAIT_LGKM();
  BARRIER();
  const int L = t >> 2, nseg = (t & 3) * 32;
  float* op = (float*)outp + (size_t)(m0 + L) * D_MODEL + n0 + nseg;
  const float* src = &Es[L * 132 + nseg];
#pragma unroll
  for (int k = 0; k < 8; k++) *(float4*)(op + 4 * k) = *(const float4*)(src + 4 * k);
}

// ---------------- flash attention, causal, no-max softmax, occupancy-first ----------------
// PROVEN VERSION (R1-R3/R7, ~45 us, passed 4x). Unchanged.
__global__ __launch_bounds__(256, 4) void attn_kernel(
    const __hip_bfloat16* __restrict__ Q, const __hip_bfloat16* __restrict__ Kg,
    const __hip_bfloat16* __restrict__ Vt, __hip_bfloat16* __restrict__ ctx) {
  const int bh = blockIdx.x;
  const int b = bh >> 4, h = bh & 15;
  const int qt = 31 - blockIdx.y;
  const int t = threadIdx.x, lane = t & 63, w = t >> 6;
  const int lr = lane & 15, lq = lane >> 4;
  const int wr = w & 1, wb = w >> 1;

  __shared__ __attribute__((aligned(16))) __hip_bfloat16 Ks[2][64 * 64];   // 8 KB each
  __shared__ __attribute__((aligned(16))) __hip_bfloat16 VTs[2][64 * 64];  // 8 KB each

  const __hip_bfloat16* Qb = Q + (size_t)bh * SEQ * HD;
  const __hip_bfloat16* Kb = Kg + (size_t)bh * SEQ * HD;
  const __hip_bfloat16* Vb = Vt + (size_t)bh * HD * SEQ;

  const int qrow0 = qt * 64 + wr * 32;  // this wave's first query row

  short8 qf[2][2];  // [rt][ks]
#pragma unroll
  for (int rt = 0; rt < 2; rt++)
#pragma unroll
    for (int ks = 0; ks < 2; ks++)
      qf[rt][ks] = *(const short8*)(Qb + (size_t)(qrow0 + rt * 16 + lr) * HD + ks * 32 + lq * 8);

  const int srow = (w << 4) + (lane >> 3);  // rows srow, srow+8
  const int sgl = lane & 7;
  const int sb0 = (w << 4) << 6;
  const int sb1 = ((w << 4) + 8) << 6;

#define STAGE(tb, nb)                                                                  \
  {                                                                                    \
    const int r0 = srow, r1 = srow + 8;                                                \
    dma16(Kb + ((size_t)((tb) + r0) << 6) + ((sgl ^ (r0 & 7)) << 3), &Ks[nb][sb0]);    \
    dma16(Kb + ((size_t)((tb) + r1) << 6) + ((sgl ^ (r1 & 7)) << 3), &Ks[nb][sb1]);    \
    dma16(Vb + (size_t)r0 * SEQ + (tb) + ((sgl ^ (r0 & 7)) << 3), &VTs[nb][sb0]);      \
    dma16(Vb + (size_t)r1 * SEQ + (tb) + ((sgl ^ (r1 & 7)) << 3), &VTs[nb][sb1]);      \
  }

  const int nkt = qt + 1;
  STAGE(0, 0);

  floatx4 o[2][4];
#pragma unroll
  for (int rt = 0; rt < 2; rt++)
#pragma unroll
    for (int dt = 0; dt < 4; dt++) o[rt][dt] = (floatx4){0.f, 0.f, 0.f, 0.f};
  floatx4 lsacc[2];
  lsacc[0] = (floatx4){0.f, 0.f, 0.f, 0.f};
  lsacc[1] = (floatx4){0.f, 0.f, 0.f, 0.f};

  short8 ones;
#pragma unroll
  for (int j = 0; j < 8; j++) ones[j] = (short)0x3F80;  // bf16 1.0

  const int kfb0 = ((wb << 4) + lr) << 6;                  // + nt*2048
  const int kg0 = ((lq ^ (lr & 7)) << 3);                  // ks=0 granule
  const int kg1 = (((4 + lq) ^ (lr & 7)) << 3);            // ks=1
  const int vga = (((wb * 2 + (lq >> 1)) ^ (lr & 7)) << 3) + ((lq & 1) << 2);
  const int vgb = (((4 + wb * 2 + (lq >> 1)) ^ (lr & 7)) << 3) + ((lq & 1) << 2);

  for (int kt = 0; kt < nkt; kt++) {
    WAIT_VM(0);
    BARRIER();
    if (kt + 1 < nkt) STAGE((kt + 1) << 6, (kt + 1) & 1);

    const int kw0 = (kt << 6) + (wb << 4);  // wave's first key
    if (kw0 <= qrow0 + 31) {
      const __hip_bfloat16* Kc = Ks[kt & 1];
      const __hip_bfloat16* Vc = VTs[kt & 1];

      short8 kf[2][2];  // [ks][nt]
#pragma unroll
      for (int nt = 0; nt < 2; nt++) {
        kf[0][nt] = *(const short8*)&Kc[(nt << 11) + kfb0 + kg0];
        kf[1][nt] = *(const short8*)&Kc[(nt << 11) + kfb0 + kg1];
      }
      floatx4 s[2][2];  // [rt][nt]
#pragma unroll
      for (int rt = 0; rt < 2; rt++)
#pragma unroll
        for (int nt = 0; nt < 2; nt++) s[rt][nt] = (floatx4){0.f, 0.f, 0.f, 0.f};
#pragma unroll
      for (int ks = 0; ks < 2; ks++)
#pragma unroll
        for (int nt = 0; nt < 2; nt++) {
          s[0][nt] = mfma_bf16(kf[ks][nt], qf[0][ks], s[0][nt]);
          s[1][nt] = mfma_bf16(kf[ks][nt], qf[1][ks], s[1][nt]);
        }

      const bool need_mask = (kw0 + 47 > qrow0);
      short8 pf[2];
#pragma unroll
      for (int rt = 0; rt < 2; rt++) {
        const int q = qrow0 + rt * 16 + lr;
        intx4 pk;
#pragma unroll
        for (int nt = 0; nt < 2; nt++) {
          const int kbase = (kt << 6) + (nt << 5) + (wb << 4) + (lq << 2);
          float x0 = s[rt][nt][0], x1 = s[rt][nt][1], x2 = s[rt][nt][2], x3 = s[rt][nt][3];
          if (need_mask) {
            x0 = (kbase + 0 <= q) ? x0 : -1e30f;
            x1 = (kbase + 1 <= q) ? x1 : -1e30f;
            x2 = (kbase + 2 <= q) ? x2 : -1e30f;
            x3 = (kbase + 3 <= q) ? x3 : -1e30f;
          }
          const float p0 = __builtin_amdgcn_exp2f(x0);
          const float p1 = __builtin_amdgcn_exp2f(x1);
          const float p2 = __builtin_amdgcn_exp2f(x2);
          const float p3 = __builtin_amdgcn_exp2f(x3);
          pk[2 * nt + 0] = cvtpk(p0, p1);
          pk[2 * nt + 1] = cvtpk(p2, p3);
        }
        pf[rt] = __builtin_bit_cast(short8, pk);
      }

      lsacc[0] = mfma_bf16(ones, pf[0], lsacc[0]);
      lsacc[1] = mfma_bf16(ones, pf[1], lsacc[1]);

#pragma unroll
      for (int dt = 0; dt < 4; dt++) {
        const int rb = ((dt << 4) + lr) << 6;
        intx4 vi;
        *(intx2*)&vi = *(const intx2*)&Vc[rb + vga];
        *(((intx2*)&vi) + 1) = *(const intx2*)&Vc[rb + vgb];
        short8 vf = __builtin_bit_cast(short8, vi);
        o[0][dt] = mfma_bf16(vf, pf[0], o[0][dt]);
        o[1][dt] = mfma_bf16(vf, pf[1], o[1][dt]);
      }
    }
  }

  BARRIER();
  if (wb == 1) {
    float* d0 = (float*)&Ks[0][0];
    float* d1 = (float*)&Ks[1][0];
    float* dl = (float*)&VTs[0][0];
    const int base = (wr << 10) + (lane << 4);
#pragma unroll
    for (int dt = 0; dt < 4; dt++) *(floatx4*)&d0[base + (dt << 2)] = o[0][dt];
#pragma unroll
    for (int dt = 0; dt < 4; dt++) *(floatx4*)&d1[base + (dt << 2)] = o[1][dt];
    dl[(wr << 7) + (lane << 1)] = lsacc[0][0];
    dl[(wr << 7) + (lane << 1) + 1] = lsacc[1][0];
    WAIT_LGKM();
  }
  BARRIER();
  if (wb == 0) {
    const float* d0 = (const float*)&Ks[0][0];
    const float* d1 = (const float*)&Ks[1][0];
    const float* dl = (const float*)&VTs[0][0];
    const int base = (wr << 10) + (lane << 4);
#pragma unroll
    for (int dt = 0; dt < 4; dt++) {
      o[0][dt] += *(const floatx4*)&d0[base + (dt << 2)];
      o[1][dt] += *(const floatx4*)&d1[base + (dt << 2)];
    }
    float inv[2];
    inv[0] = 1.f / (lsacc[0][0] + dl[(wr << 7) + (lane << 1)]);
    inv[1] = 1.f / (lsacc[1][0] + dl[(wr << 7) + (lane << 1) + 1]);
#pragma unroll
    for (int rt = 0; rt < 2; rt++) {
      const int row = qrow0 + rt * 16 + lr;
      __hip_bfloat16* cp = ctx + (size_t)b * SEQ * D_MODEL + (size_t)row * D_MODEL + h * HD;
#pragma unroll
      for (int dt = 0; dt < 4; dt++) {
        ushort4 pk;
        __hip_bfloat16* pp = (__hip_bfloat16*)&pk;
#pragma unroll
        for (int r = 0; r < 4; r++) pp[r] = __float2bfloat16(o[rt][dt][r] * inv[rt]);
        *(ushort4*)(cp + (dt << 4) + (lq << 2)) = pk;
      }
    }
  }
#undef STAGE
}

extern "C" void kernel_launch(void* const* d_in, const int* in_sizes, int n_in,
                              void* d_out, int out_size, void* d_ws, size_t ws_size,
                              hipStream_t stream) {
  const float* x  = (const float*)d_in[0];
  const float* Wq = (const float*)d_in[1];
  const float* bq = (const float*)d_in[2];
  const float* Wk = (const float*)d_in[3];
  const float* bk = (const float*)d_in[4];
  const float* Wv = (const float*)d_in[5];
  const float* bv = (const float*)d_in[6];
  const float* Wo = (const float*)d_in[7];
  const float* bo = (const float*)d_in[8];

  char* ws = (char*)d_ws;
  const size_t MB = 1u << 20;
  __hip_bfloat16* xb  = (__hip_bfloat16*)(ws + 0 * MB);   // 8 MB; reused as ctx after QKV GEMM
  __hip_bfloat16* wtq = (__hip_bfloat16*)(ws + 8 * MB);
  __hip_bfloat16* wtk = (__hip_bfloat16*)(ws + 10 * MB);
  __hip_bfloat16* wtv = (__hip_bfloat16*)(ws + 12 * MB);
  __hip_bfloat16* wto = (__hip_bfloat16*)(ws + 14 * MB);
  __hip_bfloat16* qb  = (__hip_bfloat16*)(ws + 16 * MB);
  __hip_bfloat16* kb  = (__hip_bfloat16*)(ws + 24 * MB);
  __hip_bfloat16* vt  = (__hip_bfloat16*)(ws + 32 * MB);
  __hip_bfloat16* ctx = xb;  // alias: x no longer needed after QKV projection

  prep_kernel<<<dim3(32, 32, 5), dim3(32, 8), 0, stream>>>(x, xb, Wq, Wk, Wv, Wo,
                                                           wtq, wtk, wtv, wto);
  gemm256_kernel<<<dim3(4, 3, 16), 512, 0, stream>>>(xb, wtq, wtk, wtv, bq, bk, bv,
                                                     (void*)qb, (void*)kb, (void*)vt);
  attn_kernel<<<dim3(32, 32), 256, 0, stream>>>(qb, kb, vt, ctx);
  gemm_kernel<1><<<dim3(8, 1, 64), 256, 0, stream>>>(ctx, wto, wto, wto, bo, bo, bo,
                                                     d_out, d_out, d_out);
}

// Round 9
// 183.303 us; speedup vs baseline: 1.4186x; 1.0181x over previous
//
#include <hip/hip_runtime.h>
#include <hip/hip_bf16.h>

typedef __attribute__((ext_vector_type(8))) short short8;
typedef __attribute__((ext_vector_type(4))) float floatx4;
typedef __attribute__((ext_vector_type(4))) int intx4;
typedef __attribute__((ext_vector_type(2))) int intx2;

#define D_MODEL 1024
#define SEQ     2048
#define NB      2
#define NH      16
#define HD      64
#define MROWS   4096   // NB*SEQ
#define CZ      (0.125f * 1.44269504f)   // 1/sqrt(64) * log2(e)

__device__ __forceinline__ floatx4 mfma_bf16(short8 a, short8 b, floatx4 c) {
  return __builtin_amdgcn_mfma_f32_16x16x32_bf16(a, b, c, 0, 0, 0);
}

// async global -> LDS, 16 B per lane. LDS dest = wave-uniform base + lane*16.
__device__ __forceinline__ void dma16(const __hip_bfloat16* g, __hip_bfloat16* l) {
  __builtin_amdgcn_global_load_lds(
      (const __attribute__((address_space(1))) void*)g,
      (__attribute__((address_space(3))) void*)l, 16, 0, 0);
}
#define WAIT_VM(n)  __asm__ __volatile__("s_waitcnt vmcnt(" #n ")" ::: "memory")
#define BARRIER()   __asm__ __volatile__("s_barrier" ::: "memory")
#define WAIT_LGKM() __asm__ __volatile__("s_waitcnt lgkmcnt(0)" ::: "memory")

// round-half-up bf16 pair pack (used by GEMM epilogues)
__device__ __forceinline__ int pack2bf(float a, float b) {
  unsigned ua = __builtin_bit_cast(unsigned, a) + 0x8000u;
  unsigned ub = __builtin_bit_cast(unsigned, b) + 0x8000u;
  return (int)__builtin_amdgcn_perm(ub, ua, 0x07060302u);
}

// single-instruction bf16 pair pack (RNE): dst.lo = bf16(a), dst.hi = bf16(b)
__device__ __forceinline__ int cvtpk(float a, float b) {
  int r;
  __asm__("v_cvt_pk_bf16_f32 %0, %1, %2" : "=v"(r) : "v"(a), "v"(b));
  return r;
}

// ---------------- prep: W transpose (z<4) + x fp32->bf16 (z==4) ----------------
__global__ void prep_kernel(const float* __restrict__ x, __hip_bfloat16* __restrict__ xb,
                            const float* __restrict__ W0, const float* __restrict__ W1,
                            const float* __restrict__ W2, const float* __restrict__ W3,
                            __hip_bfloat16* __restrict__ T0, __hip_bfloat16* __restrict__ T1,
                            __hip_bfloat16* __restrict__ T2, __hip_bfloat16* __restrict__ T3) {
  const int z = blockIdx.z;
  if (z == 4) {
    const int tid = threadIdx.y * 32 + threadIdx.x;
    const int base = ((blockIdx.y * 32 + blockIdx.x) * 256 + tid) * 16;
#pragma unroll
    for (int c = 0; c < 4; c++) {
      float4 v = *(const float4*)(x + base + c * 4);
      __hip_bfloat16 tmp[4];
      tmp[0] = __float2bfloat16(v.x);
      tmp[1] = __float2bfloat16(v.y);
      tmp[2] = __float2bfloat16(v.z);
      tmp[3] = __float2bfloat16(v.w);
      *(ushort4*)(xb + base + c * 4) = *(ushort4*)tmp;
    }
    return;
  }
  const float* W = (z == 0) ? W0 : (z == 1) ? W1 : (z == 2) ? W2 : W3;
  __hip_bfloat16* Wt = (z == 0) ? T0 : (z == 1) ? T1 : (z == 2) ? T2 : T3;
  __shared__ float tile[32][33];
  int k0 = blockIdx.x * 32, n0 = blockIdx.y * 32;
  int tx = threadIdx.x, ty = threadIdx.y;  // block (32,8)
#pragma unroll
  for (int i = 0; i < 4; i++)
    tile[ty + 8 * i][tx] = W[(size_t)(k0 + ty + 8 * i) * D_MODEL + n0 + tx];
  __syncthreads();
#pragma unroll
  for (int i = 0; i < 4; i++)
    Wt[(size_t)(n0 + ty + 8 * i) * D_MODEL + k0 + tx] = __float2bfloat16(tile[tx][ty + 8 * i]);
}

// ---------------- QKV GEMM: 256x256 tile, 8-phase counted-vmcnt schedule ----------------
// As R8, plus the XCD-L2 remap that R8 dropped (the R7-measured mechanism:
// FETCH 35.9->28.9 MB on the 128^2 kernel). lin = bx + 4*(by + 3*bz);
// n = lin/48, z = (lin%48)/16, m = lin%16. All 4 n-blocks of a (z,m) then share
// lin%8 -> same XCD -> each 512 KB A-tile fetched once per XCD (per-XCD A set =
// 6 x 512 KB = 3 MB, fits 4 MB L2). Bijective: 192 = 4*48 exactly.
// 512 thr = 8 waves (2M x 4N); wave owns 128x64 (acc[8][4]); BK=64;
// LDS = 2dbuf x (A 32K + B 32K) = 128 KB -> 1 block/CU. Granule swizzle
// phys_g = g ^ (row&7): linear LDS dest, inverse-swizzled global source,
// swizzled ds_read column. Counted vmcnt(2)/vmcnt(4), never 0 mid-loop.
// grid (4,3,16). z=0 -> Q bf16 [bh][s][d]*CZ; z=1 -> K; z=2 -> V^T [bh][d][s].
__global__ __launch_bounds__(512, 2) void gemm256_kernel(
    const __hip_bfloat16* __restrict__ X,
    const __hip_bfloat16* __restrict__ Wt0, const __hip_bfloat16* __restrict__ Wt1,
    const __hip_bfloat16* __restrict__ Wt2,
    const float* __restrict__ b0, const float* __restrict__ b1, const float* __restrict__ b2,
    void* __restrict__ out0, void* __restrict__ out1, void* __restrict__ out2) {
  constexpr int NKT = D_MODEL / 64;     // 16 K-steps
  constexpr int BUFE = 256 * 64;        // elems per LDS tile buffer

  // XCD-aware role remap from dispatch-linear block id (x fastest).
  const int lin = blockIdx.x + 4 * (blockIdx.y + 3 * blockIdx.z);  // 0..191
  const int n_idx = lin / 48;
  const int rem = lin - n_idx * 48;
  const int z = rem >> 4;
  const int m_idx = rem & 15;

  const __hip_bfloat16* Wt = (z == 0) ? Wt0 : (z == 1) ? Wt1 : Wt2;
  const float* bias = (z == 0) ? b0 : (z == 1) ? b1 : b2;
  void* outp = (z == 0) ? out0 : (z == 1) ? out1 : out2;
  const float scale = (z == 0) ? CZ : 1.f;

  __shared__ __attribute__((aligned(16))) char smem[131072];  // 128 KB
  __hip_bfloat16* As = (__hip_bfloat16*)smem;                 // 2 x 32 KB
  __hip_bfloat16* Bs = (__hip_bfloat16*)smem + 2 * BUFE;      // 2 x 32 KB
  float* Es = (float*)smem;                                   // epilogue scratch [64][260]

  const int n0 = n_idx * 256;
  const int m0 = m_idx * 256;
  const int t = threadIdx.x;
  const int lane = t & 63, w = t >> 6;
  const int wm = w >> 2, wn = w & 3;
  const int lr = lane & 15, lq = lane >> 4;

  const __hip_bfloat16* Xp = X + (size_t)m0 * D_MODEL;
  const __hip_bfloat16* Wp = Wt + (size_t)n0 * D_MODEL;

  // staging: one dma16 covers 64 rows (512 thr x 16B = 8 KB). Thread t handles
  // row (t>>3) of the unit, source granule inverse-swizzled.
  const int srow = t >> 3;                    // 0..63
  const int sg = (t & 7) ^ (srow & 7);        // source granule
  const int wbase = (w << 3) << 6;            // wave-uniform LDS elem base (8 rows/wave)

#define STAGE_A8(kt_, u_)                                                             \
  dma16(Xp + (size_t)(((u_) << 6) + srow) * D_MODEL + ((kt_) << 6) + (sg << 3),       \
        As + (((kt_) & 1) ? BUFE : 0) + ((u_) << 12) + wbase)
#define STAGE_B8(kt_, u_)                                                             \
  dma16(Wp + (size_t)(((u_) << 6) + srow) * D_MODEL + ((kt_) << 6) + (sg << 3),       \
        Bs + (((kt_) & 1) ? BUFE : 0) + ((u_) << 12) + wbase)

  floatx4 acc[8][4];
#pragma unroll
  for (int i = 0; i < 8; i++)
#pragma unroll
    for (int j = 0; j < 4; j++) acc[i][j] = (floatx4){0.f, 0.f, 0.f, 0.f};

  // prologue: stage kt=0 in consumption order
  STAGE_B8(0, 0); STAGE_B8(0, 1); STAGE_B8(0, 2); STAGE_B8(0, 3);
  STAGE_A8(0, 0); STAGE_A8(0, 2); STAGE_A8(0, 1); STAGE_A8(0, 3);

#define READ_A2(dst, IB)                                                              \
  _Pragma("unroll") for (int i2 = 0; i2 < 2; i2++) {                                  \
    const int ra = (wm << 7) + (((IB) + i2) << 4) + lr;                               \
    _Pragma("unroll") for (int ks = 0; ks < 2; ks++)                                  \
      dst[i2][ks] = *(const short8*)&Ac[(ra << 6) + ((((ks << 2) + lq) ^ (ra & 7)) << 3)]; \
  }
#define MFMA_Q(IB, afr)                                                               \
  __builtin_amdgcn_s_setprio(1);                                                      \
  _Pragma("unroll") for (int i2 = 0; i2 < 2; i2++)                                    \
  _Pragma("unroll") for (int j = 0; j < 4; j++) {                                     \
    acc[(IB) + i2][j] = mfma_bf16(afr[i2][0], bf[j][0], acc[(IB) + i2][j]);           \
    acc[(IB) + i2][j] = mfma_bf16(afr[i2][1], bf[j][1], acc[(IB) + i2][j]);           \
  }                                                                                   \
  __builtin_amdgcn_s_setprio(0);

  for (int kt = 0; kt < NKT; kt++) {
    const __hip_bfloat16* Ac = As + ((kt & 1) ? BUFE : 0);
    const __hip_bfloat16* Bc = Bs + ((kt & 1) ? BUFE : 0);
    const bool pre = (kt + 1 < NKT);

    // ---- phase 0: B frags + i{0,1} ----
    WAIT_VM(2);
    BARRIER();
    if (pre) { STAGE_B8(kt + 1, 0); STAGE_B8(kt + 1, 1); }
    short8 bf[4][2];
#pragma unroll
    for (int j = 0; j < 4; j++) {
      const int rb = (wn << 6) + (j << 4) + lr;
#pragma unroll
      for (int ks = 0; ks < 2; ks++)
        bf[j][ks] = *(const short8*)&Bc[(rb << 6) + ((((ks << 2) + lq) ^ (rb & 7)) << 3)];
    }
    {
      short8 a0[2][2];
      READ_A2(a0, 0);
      MFMA_Q(0, a0);
    }
    BARRIER();

    // ---- phase 1: i{2,3} ----
    if (pre) { STAGE_B8(kt + 1, 2); STAGE_B8(kt + 1, 3); }
    {
      short8 a1[2][2];
      READ_A2(a1, 2);
      MFMA_Q(2, a1);
    }
    BARRIER();

    // ---- phase 2: i{4,5} (needs Au1,Au3 of this kt) ----
    if (pre) { WAIT_VM(4); } else { WAIT_VM(0); }
    BARRIER();
    if (pre) { STAGE_A8(kt + 1, 0); STAGE_A8(kt + 1, 2); }
    {
      short8 a2[2][2];
      READ_A2(a2, 4);
      MFMA_Q(4, a2);
    }
    BARRIER();

    // ---- phase 3: i{6,7} ----
    if (pre) { STAGE_A8(kt + 1, 1); STAGE_A8(kt + 1, 3); }
    {
      short8 a3[2][2];
      READ_A2(a3, 6);
      MFMA_Q(6, a3);
    }
    BARRIER();
  }
#undef READ_A2
#undef MFMA_Q
#undef STAGE_A8
#undef STAGE_B8

  // ---- epilogue via LDS round-trip, scratch [64 rows][260] floats (~66 KB) ----
  float bvj[4];
#pragma unroll
  for (int j = 0; j < 4; j++) bvj[j] = bias[n0 + (wn << 6) + j * 16 + lr];

  if (z != 2) {
    // Q/K bf16 [bh][s][d]. 4 chunks of 64 rows (i-pairs {2c,2c+1} x both wm).
    for (int c = 0; c < 4; c++) {
      BARRIER();
#pragma unroll
      for (int i2 = 0; i2 < 2; i2++) {
        const int rowl = (wm << 5) + (i2 << 4) + (lq << 2);
#pragma unroll
        for (int j = 0; j < 4; j++)
#pragma unroll
          for (int r = 0; r < 4; r++)
            Es[(rowl + r) * 260 + (wn << 6) + j * 16 + lr] =
                (acc[2 * c + i2][j][r] + bvj[j]) * scale;
      }
      WAIT_LGKM();
      BARRIER();
      const int rl = t >> 3, cs = (t & 7) * 32;
      const int m = m0 + ((rl >> 5) << 7) + (c << 5) + (rl & 31);
      const int bb = m >> 11, s = m & 2047;
      const int n = n0 + cs;
      __hip_bfloat16* op = (__hip_bfloat16*)outp +
          (((size_t)(bb * NH + (n >> 6)) * SEQ + s) * HD + (n & 63));
      const float* src = &Es[rl * 260 + cs];
#pragma unroll
      for (int k = 0; k < 4; k++) {
        intx4 pk;
        pk[0] = pack2bf(src[8 * k + 0], src[8 * k + 1]);
        pk[1] = pack2bf(src[8 * k + 2], src[8 * k + 3]);
        pk[2] = pack2bf(src[8 * k + 4], src[8 * k + 5]);
        pk[3] = pack2bf(src[8 * k + 6], src[8 * k + 7]);
        *(intx4*)(op + 8 * k) = pk;
      }
    }
  } else {
    // V^T bf16 [bh][d][s]. 4 chunks, one j per chunk; scratch [64 n][260 m].
    for (int jj = 0; jj < 4; jj++) {
      BARRIER();
      {
        const int nc = (wn << 4) + lr;
#pragma unroll
        for (int i = 0; i < 8; i++) {
          const int ml = (wm << 7) + (i << 4) + (lq << 2);
          floatx4 v = acc[i][jj];
          v[0] += bvj[jj]; v[1] += bvj[jj]; v[2] += bvj[jj]; v[3] += bvj[jj];
          *(floatx4*)&Es[nc * 260 + ml] = v;
        }
      }
      WAIT_LGKM();
      BARRIER();
      const int nc2 = t >> 3, ms = (t & 7) * 32;
      const int n = n0 + ((nc2 >> 4) << 6) + (jj << 4) + (nc2 & 15);
      const int s0 = m0 & 2047, bb = m0 >> 11;
      __hip_bfloat16* op = (__hip_bfloat16*)outp +
          (((size_t)(bb * NH + (n >> 6)) * HD + (n & 63)) * SEQ + s0 + ms);
      const float* src = &Es[nc2 * 260 + ms];
#pragma unroll
      for (int k = 0; k < 4; k++) {
        intx4 pk;
        pk[0] = pack2bf(src[8 * k + 0], src[8 * k + 1]);
        pk[1] = pack2bf(src[8 * k + 2], src[8 * k + 3]);
        pk[2] = pack2bf(src[8 * k + 4], src[8 * k + 5]);
        pk[3] = pack2bf(src[8 * k + 6], src[8 * k + 7]);
        *(intx4*)(op + 8 * k) = pk;
      }
    }
  }
}

// ---------------- output GEMM (unchanged proven template, MODE 1 only) ----------------
template <int MODE>
__global__ __launch_bounds__(256) void gemm_kernel(
    const __hip_bfloat16* __restrict__ X,
    const __hip_bfloat16* __restrict__ Wt0, const __hip_bfloat16* __restrict__ Wt1,
    const __hip_bfloat16* __restrict__ Wt2,
    const float* __restrict__ b0, const float* __restrict__ b1, const float* __restrict__ b2,
    void* __restrict__ out0, void* __restrict__ out1, void* __restrict__ out2) {
  constexpr int MT = (MODE == 0) ? 128 : 64;
  constexpr int I = MT / 32;
  constexpr int NKT = D_MODEL / 32;
  constexpr int STAGE_BYTES = 3 * (MT * 32 + 128 * 32) * 2;
  constexpr int EPI_BYTES = 64 * 132 * 4;
  constexpr int SMEM_BYTES = (STAGE_BYTES > EPI_BYTES) ? STAGE_BYTES : EPI_BYTES;

  int n_idx, z, m_idx;
  {
    const int lin = blockIdx.x + 8 * blockIdx.z;  // 0..511 (grid y == 1)
    n_idx = lin >> 6;
    z = 0;
    m_idx = lin & 63;
  }

  const __hip_bfloat16* Wt = (z == 0) ? Wt0 : (z == 1) ? Wt1 : Wt2;
  const float* bias = (z == 0) ? b0 : (z == 1) ? b1 : b2;
  void* outp = (z == 0) ? out0 : (z == 1) ? out1 : out2;

  __shared__ __attribute__((aligned(16))) char smem[SMEM_BYTES];
  __hip_bfloat16* As = (__hip_bfloat16*)smem;
  __hip_bfloat16* Bs = (__hip_bfloat16*)smem + 3 * MT * 32;
  float* Es = (float*)smem;

  const int n0 = n_idx * 128;
  const int m0 = m_idx * MT;
  const int t = threadIdx.x;
  const int lane = t & 63, w = t >> 6;
  const int wm = (w >> 1) * (MT / 2), wn = (w & 1) * 64;
  const int lr = lane & 15;
  const int lq = lane >> 4;

  const __hip_bfloat16* Xp = X + (size_t)m0 * D_MODEL;
  const __hip_bfloat16* Wp = Wt + (size_t)n0 * D_MODEL;

  const int lrow = lane >> 2;
  const int skg = (((lane & 3) ^ ((lane >> 3) & 3)) << 3);
  const int srowA = ((MT == 128) ? (w << 5) : (w << 4)) + lrow;
  const int sbA0 = (((MT == 128) ? (w << 5) : (w << 4)) << 5);
  const int sbA1 = sbA0 + (16 << 5);
  const int srowB = (w << 5) + lrow;
  const int sbB0 = ((w << 5) << 5);
  const int sbB1 = sbB0 + (16 << 5);

#define STAGE_G(kt_, buf_)                                                              \
  {                                                                                     \
    const int kn_ = (kt_) * 32;                                                         \
    __hip_bfloat16* A_ = As + (buf_) * (MT * 32);                                       \
    __hip_bfloat16* B_ = Bs + (buf_) * (128 * 32);                                      \
    dma16(Xp + (size_t)srowA * D_MODEL + kn_ + skg, A_ + sbA0);                         \
    if (MT == 128) dma16(Xp + (size_t)(srowA + 16) * D_MODEL + kn_ + skg, A_ + sbA1);   \
    dma16(Wp + (size_t)srowB * D_MODEL + kn_ + skg, B_ + sbB0);                         \
    dma16(Wp + (size_t)(srowB + 16) * D_MODEL + kn_ + skg, B_ + sbB1);                  \
  }

  floatx4 acc[I][4];
#pragma unroll
  for (int i = 0; i < I; i++)
#pragma unroll
    for (int j = 0; j < 4; j++) acc[i][j] = (floatx4){0.f, 0.f, 0.f, 0.f};

  STAGE_G(0, 0);
  STAGE_G(1, 1);

  const int rcol = ((lq ^ ((lr >> 1) & 3)) << 3);

  int cb = 0;
  for (int kt = 0; kt < NKT; kt++) {
    if (kt < NKT - 1) {
      WAIT_VM(3);
    } else {
      WAIT_VM(0);
    }
    BARRIER();
    if (kt + 2 < NKT) {
      const int nb = (cb == 0) ? 2 : cb - 1;
      STAGE_G(kt + 2, nb);
    }
    const __hip_bfloat16* Ac = As + cb * (MT * 32);
    const __hip_bfloat16* Bc = Bs + cb * (128 * 32);
    short8 af[I], bfr[4];
#pragma unroll
    for (int i = 0; i < I; i++) af[i] = *(const short8*)&Ac[(wm + i * 16 + lr) * 32 + rcol];
#pragma unroll
    for (int j = 0; j < 4; j++) bfr[j] = *(const short8*)&Bc[(wn + j * 16 + lr) * 32 + rcol];
#pragma unroll
    for (int i = 0; i < I; i++)
#pragma unroll
      for (int j = 0; j < 4; j++) acc[i][j] = mfma_bf16(af[i], bfr[j], acc[i][j]);
    cb = (cb == 2) ? 0 : cb + 1;
  }
#undef STAGE_G

  float bvj[4];
#pragma unroll
  for (int j = 0; j < 4; j++) bvj[j] = bias[n0 + wn + j * 16 + lr];

  // fp32 row-major out. Scratch [64 m][132].
  BARRIER();
#pragma unroll
  for (int i = 0; i < I; i++) {
    const int rowb = wm + i * 16 + lq * 4;
#pragma unroll
    for (int j = 0; j < 4; j++)
#pragma unroll
      for (int r = 0; r < 4; r++)
        Es[(rowb + r) * 132 + wn + j * 16 + lr] = acc[i][j][r] + bvj[j];
  }
  WAIT_LGKM();
  BARRIER();
  const int L = t >> 2, nseg = (t & 3) * 32;
  float* op = (float*)outp + (size_t)(m0 + L) * D_MODEL + n0 + nseg;
  const float* src = &Es[L * 132 + nseg];
#pragma unroll
  for (int k = 0; k < 8; k++) *(float4*)(op + 4 * k) = *(const float4*)(src + 4 * k);
}

// ---------------- flash attention, causal, no-max softmax, occupancy-first ----------------
// PROVEN VERSION (R1-R3/R7/R8, ~45 us, passed 5x). Unchanged.
__global__ __launch_bounds__(256, 4) void attn_kernel(
    const __hip_bfloat16* __restrict__ Q, const __hip_bfloat16* __restrict__ Kg,
    const __hip_bfloat16* __restrict__ Vt, __hip_bfloat16* __restrict__ ctx) {
  const int bh = blockIdx.x;
  const int b = bh >> 4, h = bh & 15;
  const int qt = 31 - blockIdx.y;
  const int t = threadIdx.x, lane = t & 63, w = t >> 6;
  const int lr = lane & 15, lq = lane >> 4;
  const int wr = w & 1, wb = w >> 1;

  __shared__ __attribute__((aligned(16))) __hip_bfloat16 Ks[2][64 * 64];   // 8 KB each
  __shared__ __attribute__((aligned(16))) __hip_bfloat16 VTs[2][64 * 64];  // 8 KB each

  const __hip_bfloat16* Qb = Q + (size_t)bh * SEQ * HD;
  const __hip_bfloat16* Kb = Kg + (size_t)bh * SEQ * HD;
  const __hip_bfloat16* Vb = Vt + (size_t)bh * HD * SEQ;

  const int qrow0 = qt * 64 + wr * 32;  // this wave's first query row

  short8 qf[2][2];  // [rt][ks]
#pragma unroll
  for (int rt = 0; rt < 2; rt++)
#pragma unroll
    for (int ks = 0; ks < 2; ks++)
      qf[rt][ks] = *(const short8*)(Qb + (size_t)(qrow0 + rt * 16 + lr) * HD + ks * 32 + lq * 8);

  const int srow = (w << 4) + (lane >> 3);  // rows srow, srow+8
  const int sgl = lane & 7;
  const int sb0 = (w << 4) << 6;
  const int sb1 = ((w << 4) + 8) << 6;

#define STAGE(tb, nb)                                                                  \
  {                                                                                    \
    const int r0 = srow, r1 = srow + 8;                                                \
    dma16(Kb + ((size_t)((tb) + r0) << 6) + ((sgl ^ (r0 & 7)) << 3), &Ks[nb][sb0]);    \
    dma16(Kb + ((size_t)((tb) + r1) << 6) + ((sgl ^ (r1 & 7)) << 3), &Ks[nb][sb1]);    \
    dma16(Vb + (size_t)r0 * SEQ + (tb) + ((sgl ^ (r0 & 7)) << 3), &VTs[nb][sb0]);      \
    dma16(Vb + (size_t)r1 * SEQ + (tb) + ((sgl ^ (r1 & 7)) << 3), &VTs[nb][sb1]);      \
  }

  const int nkt = qt + 1;
  STAGE(0, 0);

  floatx4 o[2][4];
#pragma unroll
  for (int rt = 0; rt < 2; rt++)
#pragma unroll
    for (int dt = 0; dt < 4; dt++) o[rt][dt] = (floatx4){0.f, 0.f, 0.f, 0.f};
  floatx4 lsacc[2];
  lsacc[0] = (floatx4){0.f, 0.f, 0.f, 0.f};
  lsacc[1] = (floatx4){0.f, 0.f, 0.f, 0.f};

  short8 ones;
#pragma unroll
  for (int j = 0; j < 8; j++) ones[j] = (short)0x3F80;  // bf16 1.0

  const int kfb0 = ((wb << 4) + lr) << 6;                  // + nt*2048
  const int kg0 = ((lq ^ (lr & 7)) << 3);                  // ks=0 granule
  const int kg1 = (((4 + lq) ^ (lr & 7)) << 3);            // ks=1
  const int vga = (((wb * 2 + (lq >> 1)) ^ (lr & 7)) << 3) + ((lq & 1) << 2);
  const int vgb = (((4 + wb * 2 + (lq >> 1)) ^ (lr & 7)) << 3) + ((lq & 1) << 2);

  for (int kt = 0; kt < nkt; kt++) {
    WAIT_VM(0);
    BARRIER();
    if (kt + 1 < nkt) STAGE((kt + 1) << 6, (kt + 1) & 1);

    const int kw0 = (kt << 6) + (wb << 4);  // wave's first key
    if (kw0 <= qrow0 + 31) {
      const __hip_bfloat16* Kc = Ks[kt & 1];
      const __hip_bfloat16* Vc = VTs[kt & 1];

      short8 kf[2][2];  // [ks][nt]
#pragma unroll
      for (int nt = 0; nt < 2; nt++) {
        kf[0][nt] = *(const short8*)&Kc[(nt << 11) + kfb0 + kg0];
        kf[1][nt] = *(const short8*)&Kc[(nt << 11) + kfb0 + kg1];
      }
      floatx4 s[2][2];  // [rt][nt]
#pragma unroll
      for (int rt = 0; rt < 2; rt++)
#pragma unroll
        for (int nt = 0; nt < 2; nt++) s[rt][nt] = (floatx4){0.f, 0.f, 0.f, 0.f};
#pragma unroll
      for (int ks = 0; ks < 2; ks++)
#pragma unroll
        for (int nt = 0; nt < 2; nt++) {
          s[0][nt] = mfma_bf16(kf[ks][nt], qf[0][ks], s[0][nt]);
          s[1][nt] = mfma_bf16(kf[ks][nt], qf[1][ks], s[1][nt]);
        }

      const bool need_mask = (kw0 + 47 > qrow0);
      short8 pf[2];
#pragma unroll
      for (int rt = 0; rt < 2; rt++) {
        const int q = qrow0 + rt * 16 + lr;
        intx4 pk;
#pragma unroll
        for (int nt = 0; nt < 2; nt++) {
          const int kbase = (kt << 6) + (nt << 5) + (wb << 4) + (lq << 2);
          float x0 = s[rt][nt][0], x1 = s[rt][nt][1], x2 = s[rt][nt][2], x3 = s[rt][nt][3];
          if (need_mask) {
            x0 = (kbase + 0 <= q) ? x0 : -1e30f;
            x1 = (kbase + 1 <= q) ? x1 : -1e30f;
            x2 = (kbase + 2 <= q) ? x2 : -1e30f;
            x3 = (kbase + 3 <= q) ? x3 : -1e30f;
          }
          const float p0 = __builtin_amdgcn_exp2f(x0);
          const float p1 = __builtin_amdgcn_exp2f(x1);
          const float p2 = __builtin_amdgcn_exp2f(x2);
          const float p3 = __builtin_amdgcn_exp2f(x3);
          pk[2 * nt + 0] = cvtpk(p0, p1);
          pk[2 * nt + 1] = cvtpk(p2, p3);
        }
        pf[rt] = __builtin_bit_cast(short8, pk);
      }

      lsacc[0] = mfma_bf16(ones, pf[0], lsacc[0]);
      lsacc[1] = mfma_bf16(ones, pf[1], lsacc[1]);

#pragma unroll
      for (int dt = 0; dt < 4; dt++) {
        const int rb = ((dt << 4) + lr) << 6;
        intx4 vi;
        *(intx2*)&vi = *(const intx2*)&Vc[rb + vga];
        *(((intx2*)&vi) + 1) = *(const intx2*)&Vc[rb + vgb];
        short8 vf = __builtin_bit_cast(short8, vi);
        o[0][dt] = mfma_bf16(vf, pf[0], o[0][dt]);
        o[1][dt] = mfma_bf16(vf, pf[1], o[1][dt]);
      }
    }
  }

  BARRIER();
  if (wb == 1) {
    float* d0 = (float*)&Ks[0][0];
    float* d1 = (float*)&Ks[1][0];
    float* dl = (float*)&VTs[0][0];
    const int base = (wr << 10) + (lane << 4);
#pragma unroll
    for (int dt = 0; dt < 4; dt++) *(floatx4*)&d0[base + (dt << 2)] = o[0][dt];
#pragma unroll
    for (int dt = 0; dt < 4; dt++) *(floatx4*)&d1[base + (dt << 2)] = o[1][dt];
    dl[(wr << 7) + (lane << 1)] = lsacc[0][0];
    dl[(wr << 7) + (lane << 1) + 1] = lsacc[1][0];
    WAIT_LGKM();
  }
  BARRIER();
  if (wb == 0) {
    const float* d0 = (const float*)&Ks[0][0];
    const float* d1 = (const float*)&Ks[1][0];
    const float* dl = (const float*)&VTs[0][0];
    const int base = (wr << 10) + (lane << 4);
#pragma unroll
    for (int dt = 0; dt < 4; dt++) {
      o[0][dt] += *(const floatx4*)&d0[base + (dt << 2)];
      o[1][dt] += *(const floatx4*)&d1[base + (dt << 2)];
    }
    float inv[2];
    inv[0] = 1.f / (lsacc[0][0] + dl[(wr << 7) + (lane << 1)]);
    inv[1] = 1.f / (lsacc[1][0] + dl[(wr << 7) + (lane << 1) + 1]);
#pragma unroll
    for (int rt = 0; rt < 2; rt++) {
      const int row = qrow0 + rt * 16 + lr;
      __hip_bfloat16* cp = ctx + (size_t)b * SEQ * D_MODEL + (size_t)row * D_MODEL + h * HD;
#pragma unroll
      for (int dt = 0; dt < 4; dt++) {
        ushort4 pk;
        __hip_bfloat16* pp = (__hip_bfloat16*)&pk;
#pragma unroll
        for (int r = 0; r < 4; r++) pp[r] = __float2bfloat16(o[rt][dt][r] * inv[rt]);
        *(ushort4*)(cp + (dt << 4) + (lq << 2)) = pk;
      }
    }
  }
#undef STAGE
}

extern "C" void kernel_launch(void* const* d_in, const int* in_sizes, int n_in,
                              void* d_out, int out_size, void* d_ws, size_t ws_size,
                              hipStream_t stream) {
  const float* x  = (const float*)d_in[0];
  const float* Wq = (const float*)d_in[1];
  const float* bq = (const float*)d_in[2];
  const float* Wk = (const float*)d_in[3];
  const float* bk = (const float*)d_in[4];
  const float* Wv = (const float*)d_in[5];
  const float* bv = (const float*)d_in[6];
  const float* Wo = (const float*)d_in[7];
  const float* bo = (const float*)d_in[8];

  char* ws = (char*)d_ws;
  const size_t MB = 1u << 20;
  __hip_bfloat16* xb  = (__hip_bfloat16*)(ws + 0 * MB);   // 8 MB; reused as ctx after QKV GEMM
  __hip_bfloat16* wtq = (__hip_bfloat16*)(ws + 8 * MB);
  __hip_bfloat16* wtk = (__hip_bfloat16*)(ws + 10 * MB);
  __hip_bfloat16* wtv = (__hip_bfloat16*)(ws + 12 * MB);
  __hip_bfloat16* wto = (__hip_bfloat16*)(ws + 14 * MB);
  __hip_bfloat16* qb  = (__hip_bfloat16*)(ws + 16 * MB);
  __hip_bfloat16* kb  = (__hip_bfloat16*)(ws + 24 * MB);
  __hip_bfloat16* vt  = (__hip_bfloat16*)(ws + 32 * MB);
  __hip_bfloat16* ctx = xb;  // alias: x no longer needed after QKV projection

  prep_kernel<<<dim3(32, 32, 5), dim3(32, 8), 0, stream>>>(x, xb, Wq, Wk, Wv, Wo,
                                                           wtq, wtk, wtv, wto);
  gemm256_kernel<<<dim3(4, 3, 16), 512, 0, stream>>>(xb, wtq, wtk, wtv, bq, bk, bv,
                                                     (void*)qb, (void*)kb, (void*)vt);
  attn_kernel<<<dim3(32, 32), 256, 0, stream>>>(qb, kb, vt, ctx);
  gemm_kernel<1><<<dim3(8, 1, 64), 256, 0, stream>>>(ctx, wto, wto, wto, bo, bo, bo,
                                                     d_out, d_out, d_out);
}